// Round 7
// baseline (206.509 us; speedup 1.0000x reference)
//
#include <hip/hip_runtime.h>
#include <cstdint>
#include <cstddef>

// ---------------------------------------------------------------------------
// DANet dual-attention head on MI355X.
// This round: conv3x3 v3 — 2 blocks/CU (52 KB LDS), per-tap W double-buffer,
// phase-robust XOR key ((c^(c>>3))&7), swizzle applied at LDS write so global
// activation layouts stay linear.
// ---------------------------------------------------------------------------

using s16x8 = __attribute__((ext_vector_type(8))) short;
using u16x8 = __attribute__((ext_vector_type(8))) unsigned short;
using u16x4 = __attribute__((ext_vector_type(4))) unsigned short;
using f32x4 = __attribute__((ext_vector_type(4))) float;
using f32x16 = __attribute__((ext_vector_type(16))) float;
using u32x4v = __attribute__((ext_vector_type(4))) unsigned;

__device__ __forceinline__ f32x4 mfma16(u16x8 a, u16x8 b, f32x4 c) {
  return __builtin_amdgcn_mfma_f32_16x16x32_bf16(
      __builtin_bit_cast(s16x8, a), __builtin_bit_cast(s16x8, b), c, 0, 0, 0);
}
__device__ __forceinline__ f32x16 mfma32(u16x8 a, u16x8 b, f32x16 c) {
  return __builtin_amdgcn_mfma_f32_32x32x16_bf16(
      __builtin_bit_cast(s16x8, a), __builtin_bit_cast(s16x8, b), c, 0, 0, 0);
}
__device__ __forceinline__ float bf2f(unsigned short u) {
  return __builtin_bit_cast(float, (unsigned)u << 16);
}
__device__ __forceinline__ unsigned short f2bf(float f) {  // RNE
  unsigned u = __builtin_bit_cast(unsigned, f);
  u += 0x7fffu + ((u >> 16) & 1u);
  return (unsigned short)(u >> 16);
}
__device__ __forceinline__ unsigned cvt_pk_bf16(float lo, float hi) {
  unsigned r;
  asm("v_cvt_pk_bf16_f32 %0, %1, %2" : "=v"(r) : "v"(lo), "v"(hi));
  return r;
}
__device__ __forceinline__ u16x8 ld8(const unsigned short* p) {
  return *reinterpret_cast<const u16x8*>(p);
}
__device__ __forceinline__ void gload16(const void* g, void* l) {
  __builtin_amdgcn_global_load_lds(
      (const __attribute__((address_space(1))) void*)g,
      (__attribute__((address_space(3))) void*)l, 16, 0, 0);
}

// ---------------- workspace layout (bytes) ----------------
#define OFF_XT    ((size_t)0)           // [4][8][66][72][64] bf16 = 19,464,192 (Gp aliases)
#define OFF_FP1   ((size_t)19464192)    // [4][2][66][72][64] bf16 = 4,866,048
#define OFF_FC1   ((size_t)24330240)
#define ZERO_BYTES ((size_t)29196288)
#define OFF_FP0   ((size_t)29196288)    // [4][4096][128] bf16 = 4,194,304 (flat)
#define OFF_FC0   ((size_t)33390592)
#define OFF_FP2   ((size_t)37584896)    // flat; Q/K alias here before conv2
#define OFF_FC2   ((size_t)41779200)    // flat; V aliases here before conv2
#define OFF_WT1   ((size_t)45973504)    // [2][2][8][9][64][64] bf16 = 2,359,296
#define OFF_WT2   ((size_t)48332800)    // [2][2][2][9][64][64] bf16 = 589,824
#define OFF_QKW   ((size_t)48922624)    // [2][16][128] bf16 = 8,192
#define OFF_VWW   ((size_t)48930816)    // [128][128] bf16 = 32,768
#define OFF_HWW   ((size_t)48963584)    // [3][32][128] bf16 = 24,576
#define OFF_BNSS  ((size_t)48988160)    // 8*128 f32 = 4,096
#define OFF_ATTN  ((size_t)48992256)    // [4][128][128] bf16 = 131,072
#define OFF_Q     OFF_FP2               // [4][4096][16] = 524,288
#define OFF_K     (OFF_FP2 + 524288)
#define OFF_V     OFF_FC2               // [4][512][128][8] m-blocked = 4,194,304

// ---------------- x: NCHW fp32 -> chunked NHWC bf16 padded (linear) -------
__global__ __launch_bounds__(256) void k_xpose(const float* __restrict__ x,
                                               unsigned short* __restrict__ xt) {
  __shared__ float tile[128][65];
  const int t = threadIdx.x;
  const int blk = blockIdx.x;  // 4b * 64h * 4cb
  const int cb = blk & 3;
  const int h = (blk >> 2) & 63;
  const int b = blk >> 8;
  const float* src = x + ((size_t)(b * 512 + cb * 128) * 64 + h) * 64;
  const int w = t & 63, cr = t >> 6;
  for (int i = 0; i < 32; ++i) tile[cr + i * 4][w] = src[(size_t)(cr + i * 4) * 4096 + w];
  __syncthreads();
  const int w2 = t >> 2, cg = t & 3;
  const int cic = cb * 2 + (cg >> 1);
  unsigned short* dst =
      xt + (((size_t)(b * 8 + cic) * 66 + h + 1) * 72 + (w2 + 1)) * 64 + (cg & 1) * 32;
#pragma unroll
  for (int j = 0; j < 32; j += 4) {
    u16x4 pk;
    pk[0] = f2bf(tile[cg * 32 + j + 0][w2]);
    pk[1] = f2bf(tile[cg * 32 + j + 1][w2]);
    pk[2] = f2bf(tile[cg * 32 + j + 2][w2]);
    pk[3] = f2bf(tile[cg * 32 + j + 3][w2]);
    *reinterpret_cast<u16x4*>(dst + j) = pk;
  }
}

// ---------------- weight / BN pre-pack ----------------
// wt layouts: [br][coHalf][cic][tap][co64][ci64], ci pre-swizzled with
// key ((co ^ (co>>3)) & 7) << 3 (gload dest must be linear).
struct PackArgs {
  const float *wp1, *wc1, *wp2, *wc2, *qw, *kw, *vw, *clsw, *apw, *acw;
  const float *g1p, *b1p, *m1p, *v1p, *g1c, *b1c, *m1c, *v1c;
  const float *g2p, *b2p, *m2p, *v2p, *g2c, *b2c, *m2c, *v2c;
  unsigned short *wt1, *wt2, *qkw, *vww, *hww;
  float* bnss;
};
__global__ __launch_bounds__(256) void k_pack(PackArgs A) {
  const int i = blockIdx.x * 256 + threadIdx.x;
  const int N1 = 2 * 2 * 8 * 9 * 64 * 64;   // 1,179,648
  const int N2 = N1 + 2 * 2 * 2 * 9 * 64 * 64;
  const int N3 = N2 + 2 * 16 * 128;
  const int N4 = N3 + 128 * 128;
  const int N5 = N4 + 3 * 32 * 128;
  const int N6 = N5 + 8 * 128;
  if (i < N1) {  // wt1
    int ci = i & 63, co64 = (i >> 6) & 63;
    int rest = i >> 12;
    int tap = rest % 9, rest2 = rest / 9;
    int cic = rest2 & 7, chh = (rest2 >> 3) & 1, brr = rest2 >> 4;
    const float* s = brr ? A.wc1 : A.wp1;
    int co = chh * 64 + co64;
    int cis = ci ^ (((co ^ (co >> 3)) & 7) << 3);
    A.wt1[i] = f2bf(s[(size_t)(co * 512 + cic * 64 + cis) * 9 + tap]);
  } else if (i < N2) {  // wt2
    int k = i - N1;
    int ci = k & 63, co64 = (k >> 6) & 63;
    int rest = k >> 12;
    int tap = rest % 9, rest2 = rest / 9;
    int cic = rest2 & 1, chh = (rest2 >> 1) & 1, brr = rest2 >> 2;
    const float* s = brr ? A.wc2 : A.wp2;
    int co = chh * 64 + co64;
    int cis = ci ^ (((co ^ (co >> 3)) & 7) << 3);
    A.wt2[k] = f2bf(s[(size_t)(co * 128 + cic * 64 + cis) * 9 + tap]);
  } else if (i < N3) {
    int k = i - N2;
    int ci = k & 127, q = k >> 7;
    const float* s = (q < 16) ? A.qw : A.kw;
    A.qkw[k] = f2bf(s[(q & 15) * 128 + ci]);
  } else if (i < N4) {
    int k = i - N3;
    A.vww[k] = f2bf(A.vw[k]);
  } else if (i < N5) {
    int k = i - N4;
    int ci = k & 127, co = (k >> 7) & 31, hd = k >> 12;
    const float* s = hd == 0 ? A.clsw : (hd == 1 ? A.apw : A.acw);
    A.hww[k] = (co < 19) ? f2bf(s[co * 128 + ci]) : (unsigned short)0;
  } else if (i < N6) {
    int k = i - N5;
    int j = k & 127, seg = k >> 7;
    const float *g, *bb, *mm, *vv;
    switch (seg >> 1) {
      case 0: g = A.g1p; bb = A.b1p; mm = A.m1p; vv = A.v1p; break;
      case 1: g = A.g1c; bb = A.b1c; mm = A.m1c; vv = A.v1c; break;
      case 2: g = A.g2p; bb = A.b2p; mm = A.m2p; vv = A.v2p; break;
      default: g = A.g2c; bb = A.b2c; mm = A.m2c; vv = A.v2c; break;
    }
    float sc = g[j] * rsqrtf(vv[j] + 1e-5f);
    A.bnss[k] = (seg & 1) ? (bb[j] - mm[j] * sc) : sc;
  }
}

// ---------------- 3x3 conv v3: 128n x 64co blocks, per-tap W dbuf ---------
// 4 waves, wave = 32n x 64co (M1,N2).  A window [4][72][64] = 36 KB,
// write-swizzled; W per tap [64co][64ci] = 8 KB x2, pre-swizzled in global.
// Grid 512 -> 2 blocks/CU.  One barrier per tap.
template <int NCHUNK>
__global__ __launch_bounds__(256, 2) void k_conv3x3(
    const unsigned short* __restrict__ in0, const unsigned short* __restrict__ in1,
    const unsigned short* __restrict__ wt, const float* __restrict__ bnb,
    unsigned short* __restrict__ out0, unsigned short* __restrict__ out1) {
  __shared__ unsigned short Awin[4 * 72 * 64];  // 36 KB
  __shared__ unsigned short Wbuf[2][64 * 64];   // 2 x 8 KB
  const int bid = blockIdx.x;
  const int ch = bid & 1;
  const int ht = (bid >> 1) & 31;
  const int b = (bid >> 6) & 3;
  const int br = bid >> 8;
  const unsigned short* inp = br ? in1 : in0;
  const unsigned short* wbr = wt + (size_t)(br * 2 + ch) * NCHUNK * 9 * 64 * 64;
  const float* scale = bnb + br * 256;
  const float* shiftp = scale + 128;
  unsigned short* outp = br ? out1 : out0;
  const int tid = threadIdx.x;
  const int lane = tid & 63, wv = tid >> 6;
  const int l31 = lane & 31, hi = lane >> 5;
  const int hi16 = hi * 16;
  const int h0 = ht * 2;
  const int cog = ch * 64;

  const int n = wv * 32 + l31;          // this lane's A row
  const int oh = n >> 6, w = n & 63;

  f32x16 acc[2];
  acc[0] = (f32x16)0.f;
  acc[1] = (f32x16)0.f;

  u16x8 streg[9];
  auto sloadA = [&](int c) {  // window rows h0..h0+3, linear global
    const char* sr =
        (const char*)(inp + (((size_t)(b * NCHUNK + c) * 66 + h0) * 72) * 64);
#pragma unroll
    for (int i = 0; i < 9; ++i)
      streg[i] = *(const u16x8*)(sr + i * 4096 + tid * 16);
  };
  auto swriteA = [&]() {  // swizzle applied at write
    char* dp = (char*)Awin;
#pragma unroll
    for (int i = 0; i < 9; ++i) {
      int g = i * 32 + (tid >> 3);  // 128B group 0..287
      int row = g / 72;
      int col = g - row * 72;
      int key = ((col ^ (col >> 3)) & 7) << 4;
      *(u16x8*)(dp + g * 128 + (((tid & 7) * 16) ^ key)) = streg[i];
    }
  };
  auto stageW = [&](int bi, int T) {  // 8 KB linear copy (pre-swizzled global)
    const char* src = (const char*)wbr + (size_t)T * 8192;
    char* dst = (char*)&Wbuf[bi][0];
#pragma unroll
    for (int i = 0; i < 2; ++i)
      gload16(src + (wv * 2 + i) * 1024 + lane * 16, dst + (wv * 2 + i) * 1024);
  };
  auto compute_tap = [&](int ty, int tx, int bi) {
    const char* ab = (const char*)Awin;
    const char* wb = (const char*)&Wbuf[bi][0];
    const int wc = w + tx;
    const int abase = ((oh + ty) * 72 + wc) << 7;
    const int akey = ((wc ^ (wc >> 3)) & 7) << 4;
    const int c0 = l31, c1 = 32 + l31;
    const int b0 = c0 * 128, k0 = ((c0 ^ (c0 >> 3)) & 7) << 4;
    const int b1 = c1 * 128, k1 = ((c1 ^ (c1 >> 3)) & 7) << 4;
#pragma unroll
    for (int s = 0; s < 4; ++s) {
      const int ko = s * 32 + hi16;
      u16x8 av = *(const u16x8*)(ab + abase + (ko ^ akey));
      u16x8 bv0 = *(const u16x8*)(wb + b0 + (ko ^ k0));
      u16x8 bv1 = *(const u16x8*)(wb + b1 + (ko ^ k1));
      acc[0] = mfma32(av, bv0, acc[0]);
      acc[1] = mfma32(av, bv1, acc[1]);
    }
  };

  // prologue
  sloadA(0);
  swriteA();  // compiler inserts vmcnt waits for streg
  stageW(0, 0);
  asm volatile("s_waitcnt vmcnt(0) lgkmcnt(0)\ns_barrier" ::: "memory");

#pragma unroll 1
  for (int c = 0; c < NCHUNK; ++c) {
#pragma unroll
    for (int t = 0; t < 9; ++t) {
      const int T = c * 9 + t;
      if (T + 1 < NCHUNK * 9) stageW((T + 1) & 1, T + 1);
      const bool ldA = (t == 3 && c + 1 < NCHUNK);
      if (ldA) sloadA(c + 1);
      compute_tap(t / 3, t % 3, T & 1);
      if (T + 1 < NCHUNK * 9) {
        if (ldA)
          asm volatile("s_waitcnt vmcnt(9) lgkmcnt(0)\ns_barrier" ::: "memory");
        else
          asm volatile("s_waitcnt vmcnt(0) lgkmcnt(0)\ns_barrier" ::: "memory");
        if (t == 8) {  // chunk boundary: rewrite A window
          swriteA();
          asm volatile("s_waitcnt lgkmcnt(0)\ns_barrier" ::: "memory");
        }
      }
    }
  }

  // epilogue: BN + ReLU + flat NHWC store
#pragma unroll
  for (int nf = 0; nf < 2; ++nf) {
    const int co = cog + nf * 32 + l31;
    const float sc = scale[co], sh = shiftp[co];
#pragma unroll
    for (int r = 0; r < 16; ++r) {
      int nr = wv * 32 + (r & 3) + 8 * (r >> 2) + 4 * hi;
      float y = acc[nf][r] * sc + sh;
      y = y > 0.f ? y : 0.f;
      outp[((size_t)b * 4096 + (size_t)(h0 + (nr >> 6)) * 64 + (nr & 63)) * 128 + co] =
          f2bf(y);
    }
  }
}

// ---------------- PAM Q/K/V 1x1 projections (MFMA) ----------------
__global__ __launch_bounds__(256) void k_qkv(
    const unsigned short* __restrict__ fp0, const unsigned short* __restrict__ qkw,
    const unsigned short* __restrict__ vww, const float* __restrict__ qb,
    const float* __restrict__ kb, const float* __restrict__ vb,
    unsigned short* __restrict__ Q, unsigned short* __restrict__ K,
    unsigned short* __restrict__ V2) {
  const int bid = blockIdx.x;
  const int nt = bid & 63, b = bid >> 6;
  const int lane = threadIdx.x & 63, wv = threadIdx.x >> 6;
  const int lg = lane >> 4, l15 = lane & 15;
  const int n = nt * 64 + wv * 16 + l15;
  const unsigned short* fbase = fp0 + ((size_t)b * 4096 + n) * 128 + lg * 8;
  f32x4 vacc[8];
#pragma unroll
  for (int mf = 0; mf < 8; ++mf) vacc[mf] = (f32x4){0.f, 0.f, 0.f, 0.f};
  f32x4 qacc = {0.f, 0.f, 0.f, 0.f}, kacc = {0.f, 0.f, 0.f, 0.f};
#pragma unroll
  for (int kc = 0; kc < 128; kc += 32) {
    u16x8 fb = ld8(fbase + kc);
    u16x8 qa = ld8(qkw + (size_t)l15 * 128 + lg * 8 + kc);
    u16x8 ka = ld8(qkw + 2048 + (size_t)l15 * 128 + lg * 8 + kc);
    qacc = mfma16(qa, fb, qacc);
    kacc = mfma16(ka, fb, kacc);
#pragma unroll
    for (int mf = 0; mf < 8; ++mf) {
      u16x8 va = ld8(vww + (size_t)(mf * 16 + l15) * 128 + lg * 8 + kc);
      vacc[mf] = mfma16(va, fb, vacc[mf]);
    }
  }
  const float LOG2E = 1.44269504088896f;
#pragma unroll
  for (int r = 0; r < 4; ++r) {
    int cq = lg * 4 + r;
    Q[(size_t)(b * 4096 + n) * 16 + cq] = f2bf((qacc[r] + qb[cq]) * LOG2E);
    K[(size_t)(b * 4096 + n) * 16 + cq] = f2bf(kacc[r] + kb[cq]);
  }
#pragma unroll
  for (int mf = 0; mf < 8; ++mf)
#pragma unroll
    for (int r = 0; r < 4; ++r) {
      int c = mf * 16 + lg * 4 + r;
      V2[((size_t)(b * 512 + (n >> 3)) * 128 + c) * 8 + (n & 7)] =
          f2bf(vacc[mf][r] + vb[c]);
    }
}

// ---------------- PAM attention: split-m, register-only body --------------
__global__ __launch_bounds__(512, 1) void k_pam(
    const unsigned short* __restrict__ Q, const unsigned short* __restrict__ K,
    const unsigned short* __restrict__ V2, const unsigned short* __restrict__ fp0,
    unsigned short* __restrict__ fp1, const float* __restrict__ pg) {
  __shared__ float obuf[2][3][16][64][4];  // 96 KB partial-O
  __shared__ float lred[8][64];            // denom partials
  const int bid = blockIdx.x;  // 4b * 64qt
  const int qt = bid & 63, b = bid >> 6;
  const int tid = threadIdx.x;
  const int lane = tid & 63, wv = tid >> 6;
  const int qsub = wv >> 2, mq = wv & 3;
  const int l31 = lane & 31, hi = lane >> 5;
  const int q0 = qt * 64 + qsub * 32;
  const unsigned short* Qp = Q + (size_t)b * 65536;
  const unsigned short* Kp = K + (size_t)b * 65536;
  const unsigned short* Vp = V2 + (size_t)b * 524288;
  const int hi8 = hi * 8;

  const u16x8 qB = ld8(Qp + (size_t)(q0 + l31) * 16 + hi8);

  f32x16 oacc[4];
#pragma unroll
  for (int ch = 0; ch < 4; ++ch) oacc[ch] = (f32x16)0.f;
  float dsum = 0.f;

  auto loadK = [&](int t) -> u16x8 {
    return ld8(Kp + (size_t)(t * 32 + l31) * 16 + hi8);
  };
  auto loadV = [&](int t, u16x8 (&vf)[8]) {
#pragma unroll
    for (int kc = 0; kc < 2; ++kc)
#pragma unroll
      for (int ch = 0; ch < 4; ++ch)
        vf[kc * 4 + ch] =
            ld8(Vp + (size_t)(t * 4 + kc * 2 + hi) * 1024 + (ch * 32 + l31) * 8);
  };
  auto body = [&](u16x8 kA, u16x8 (&vf)[8]) {
    f32x16 pacc = mfma32(kA, qB, (f32x16)0.f);
    float p[16];
#pragma unroll
    for (int r = 0; r < 16; ++r) p[r] = exp2f(pacc[r]);
    dsum += (((p[0] + p[1]) + (p[2] + p[3])) + ((p[4] + p[5]) + (p[6] + p[7]))) +
            (((p[8] + p[9]) + (p[10] + p[11])) + ((p[12] + p[13]) + (p[14] + p[15])));
    unsigned X[8], S[8];
#pragma unroll
    for (int j = 0; j < 8; ++j) X[j] = cvt_pk_bf16(p[2 * j], p[2 * j + 1]);
#pragma unroll
    for (int j = 0; j < 8; ++j) S[j] = __shfl_xor(X[j], 32, 64);
    const bool hc = hi != 0;
    u32x4v w0, w1;
    w0[0] = hc ? S[2] : X[0];
    w0[1] = hc ? S[3] : X[1];
    w0[2] = hc ? X[2] : S[0];
    w0[3] = hc ? X[3] : S[1];
    w1[0] = hc ? S[6] : X[4];
    w1[1] = hc ? S[7] : X[5];
    w1[2] = hc ? X[6] : S[4];
    w1[3] = hc ? X[7] : S[5];
    u16x8 f0 = __builtin_bit_cast(u16x8, w0);
    u16x8 f1 = __builtin_bit_cast(u16x8, w1);
#pragma unroll
    for (int ch = 0; ch < 4; ++ch) oacc[ch] = mfma32(f0, vf[ch], oacc[ch]);
#pragma unroll
    for (int ch = 0; ch < 4; ++ch) oacc[ch] = mfma32(f1, vf[4 + ch], oacc[ch]);
  };

  const int t0 = mq * 32;
  u16x8 kA0 = loadK(t0), kA1;
  u16x8 vf0[8], vf1[8];
  loadV(t0, vf0);
#pragma unroll 1
  for (int t = 0; t < 32; t += 2) {
    kA1 = loadK(t0 + t + 1);
    loadV(t0 + t + 1, vf1);
    body(kA0, vf0);
    if (t + 2 < 32) {
      kA0 = loadK(t0 + t + 2);
      loadV(t0 + t + 2, vf0);
    }
    body(kA1, vf1);
  }

  dsum += __shfl_xor(dsum, 32, 64);
  lred[wv][lane] = dsum;
  if (mq) {
#pragma unroll
    for (int ch = 0; ch < 4; ++ch)
#pragma unroll
      for (int j = 0; j < 4; ++j) {
        f32x4 v = {oacc[ch][4 * j + 0], oacc[ch][4 * j + 1], oacc[ch][4 * j + 2],
                   oacc[ch][4 * j + 3]};
        *reinterpret_cast<f32x4*>(&obuf[qsub][mq - 1][ch * 4 + j][lane][0]) = v;
      }
  }
  __syncthreads();
  if (mq == 0) {
    const float dtot = lred[qsub * 4 + 0][lane] + lred[qsub * 4 + 1][lane] +
                       lred[qsub * 4 + 2][lane] + lred[qsub * 4 + 3][lane];
#pragma unroll
    for (int ch = 0; ch < 4; ++ch)
#pragma unroll
      for (int j = 0; j < 4; ++j) {
        f32x4 s0 = *reinterpret_cast<const f32x4*>(&obuf[qsub][0][ch * 4 + j][lane][0]);
        f32x4 s1 = *reinterpret_cast<const f32x4*>(&obuf[qsub][1][ch * 4 + j][lane][0]);
        f32x4 s2 = *reinterpret_cast<const f32x4*>(&obuf[qsub][2][ch * 4 + j][lane][0]);
#pragma unroll
        for (int r = 0; r < 4; ++r)
          oacc[ch][4 * j + r] += (s0[r] + s1[r]) + s2[r];
      }
    const float rden = 1.f / dtot;
    const float gm = pg[0];
    float rdr[16];
#pragma unroll
    for (int r = 0; r < 16; ++r)
      rdr[r] = __shfl(rden, (r & 3) + 8 * (r >> 2) + 4 * hi, 64);
#pragma unroll
    for (int ch = 0; ch < 4; ++ch) {
      const int c = ch * 32 + l31;
#pragma unroll
      for (int r = 0; r < 16; ++r) {
        const int n = q0 + (r & 3) + 8 * (r >> 2) + 4 * hi;
        float o = gm * oacc[ch][r] * rdr[r] +
                  bf2f(fp0[((size_t)b * 4096 + n) * 128 + c]);
        fp1[(((size_t)(b * 2 + (c >> 6)) * 66 + (n >> 6) + 1) * 72 + ((n & 63) + 1)) *
                64 +
            (c & 63)] = f2bf(o);
      }
    }
  }
}

// ---------------- CAM Gram partials (fp32 VALU) ----------------
__global__ __launch_bounds__(256) void k_gram(const unsigned short* __restrict__ fc0,
                                              float* __restrict__ Gp) {
  __shared__ float fl[32][132];
  const int bid = blockIdx.x;
  const int nc = bid & 63, b = bid >> 6;
  const int t = threadIdx.x;
  const int i = t >> 1, jh = (t & 1) * 64;
  float acc[64];
#pragma unroll
  for (int j = 0; j < 64; ++j) acc[j] = 0.f;
  for (int c2 = 0; c2 < 2; ++c2) {
    const int n0 = nc * 64 + c2 * 32;
    {
      int nn = t >> 3, kh = t & 7;
      const unsigned short* src = fc0 + ((size_t)b * 4096 + n0 + nn) * 128 + kh * 16;
      u16x8 v0 = ld8(src), v1 = ld8(src + 8);
#pragma unroll
      for (int e = 0; e < 8; ++e) {
        fl[nn][kh * 16 + e] = bf2f(v0[e]);
        fl[nn][kh * 16 + 8 + e] = bf2f(v1[e]);
      }
    }
    __syncthreads();
    for (int nn = 0; nn < 32; ++nn) {
      float fi = fl[nn][i];
      const float4* row = reinterpret_cast<const float4*>(&fl[nn][jh]);
#pragma unroll
      for (int j4 = 0; j4 < 16; ++j4) {
        float4 fv = row[j4];
        acc[4 * j4 + 0] += fi * fv.x;
        acc[4 * j4 + 1] += fi * fv.y;
        acc[4 * j4 + 2] += fi * fv.z;
        acc[4 * j4 + 3] += fi * fv.w;
      }
    }
    __syncthreads();
  }
  float* dst = Gp + (((size_t)b * 64 + nc) * 128 + i) * 128 + jh;
  float4* dst4 = reinterpret_cast<float4*>(dst);
#pragma unroll
  for (int j4 = 0; j4 < 16; ++j4)
    dst4[j4] = make_float4(acc[4 * j4], acc[4 * j4 + 1], acc[4 * j4 + 2], acc[4 * j4 + 3]);
}

// ---------------- CAM reduce + softmax (fp32) ----------------
__global__ __launch_bounds__(128) void k_softm(const float* __restrict__ Gp,
                                               unsigned short* __restrict__ attn) {
  const int bid = blockIdx.x;
  const int i = bid & 127, b = bid >> 7;
  const int j = threadIdx.x;
  float g = 0.f;
  for (int nc = 0; nc < 64; ++nc) g += Gp[(((size_t)b * 64 + nc) * 128 + i) * 128 + j];
  __shared__ float red[2], red2[2];
  float m = g;
  m = fmaxf(m, __shfl_xor(m, 1, 64));
  m = fmaxf(m, __shfl_xor(m, 2, 64));
  m = fmaxf(m, __shfl_xor(m, 4, 64));
  m = fmaxf(m, __shfl_xor(m, 8, 64));
  m = fmaxf(m, __shfl_xor(m, 16, 64));
  m = fmaxf(m, __shfl_xor(m, 32, 64));
  const int wvi = j >> 6;
  if ((j & 63) == 0) red[wvi] = m;
  __syncthreads();
  m = fmaxf(red[0], red[1]);
  float e = __expf(g - m);
  float s = e;
  s += __shfl_xor(s, 1, 64);
  s += __shfl_xor(s, 2, 64);
  s += __shfl_xor(s, 4, 64);
  s += __shfl_xor(s, 8, 64);
  s += __shfl_xor(s, 16, 64);
  s += __shfl_xor(s, 32, 64);
  if ((j & 63) == 0) red2[wvi] = s;
  __syncthreads();
  s = red2[0] + red2[1];
  attn[((size_t)b * 128 + i) * 128 + j] = f2bf(e / s);
}

// ---------------- CAM out: attn @ f, residual (MFMA) ----------------
__global__ __launch_bounds__(256) void k_camout(
    const unsigned short* __restrict__ fc0, const unsigned short* __restrict__ attn,
    const float* __restrict__ cg, unsigned short* __restrict__ fc1) {
  const int bid = blockIdx.x;
  const int nt = bid & 63, b = bid >> 6;
  const int lane = threadIdx.x & 63, wv = threadIdx.x >> 6;
  const int lg = lane >> 4, l15 = lane & 15;
  const int n = nt * 64 + wv * 16 + l15;
  const unsigned short* fbase = fc0 + ((size_t)b * 4096 + n) * 128 + lg * 8;
  const unsigned short* abase = attn + (size_t)b * 16384 + lg * 8;
  f32x4 acc[8];
#pragma unroll
  for (int mf = 0; mf < 8; ++mf) acc[mf] = (f32x4){0.f, 0.f, 0.f, 0.f};
#pragma unroll
  for (int kc = 0; kc < 128; kc += 32) {
    u16x8 fb = ld8(fbase + kc);
#pragma unroll
    for (int mf = 0; mf < 8; ++mf) {
      u16x8 aa = ld8(abase + (size_t)(mf * 16 + l15) * 128 + kc);
      acc[mf] = mfma16(aa, fb, acc[mf]);
    }
  }
  const float gm = cg[0];
  const int nn = nt * 64 + wv * 16 + l15;
#pragma unroll
  for (int mf = 0; mf < 8; ++mf)
#pragma unroll
    for (int r = 0; r < 4; ++r) {
      int c = mf * 16 + lg * 4 + r;
      float o = gm * acc[mf][r] + bf2f(fc0[((size_t)b * 4096 + nn) * 128 + c]);
      fc1[(((size_t)(b * 2 + (c >> 6)) * 66 + (nn >> 6) + 1) * 72 + (nn & 63) + 1) * 64 +
          (c & 63)] = f2bf(o);
    }
}

// ---------------- classifier heads (MFMA, fp32 out) ----------------
__global__ __launch_bounds__(256) void k_heads(
    const unsigned short* __restrict__ fp2, const unsigned short* __restrict__ fc2,
    const unsigned short* __restrict__ hw, const float* __restrict__ clsb,
    const float* __restrict__ apb, const float* __restrict__ acb,
    float* __restrict__ out) {
  const int bid = blockIdx.x;
  const int nt = bid & 63, b = bid >> 6;
  const int lane = threadIdx.x & 63, wv = threadIdx.x >> 6;
  const int lg = lane >> 4, l15 = lane & 15;
  const int n = nt * 64 + wv * 16 + l15;
  const unsigned short* pb = fp2 + (size_t)(b * 4096 + n) * 128 + lg * 8;
  const unsigned short* cb = fc2 + (size_t)(b * 4096 + n) * 128 + lg * 8;
  f32x4 acc[3][2];
#pragma unroll
  for (int hd = 0; hd < 3; ++hd)
#pragma unroll
    for (int mf = 0; mf < 2; ++mf) acc[hd][mf] = (f32x4){0.f, 0.f, 0.f, 0.f};
#pragma unroll
  for (int kc = 0; kc < 128; kc += 32) {
    u16x8 vp = ld8(pb + kc);
    u16x8 vc = ld8(cb + kc);
    u16x8 vs;
#pragma unroll
    for (int e = 0; e < 8; ++e) vs[e] = f2bf(bf2f(vp[e]) + bf2f(vc[e]));
#pragma unroll
    for (int mf = 0; mf < 2; ++mf) {
      u16x8 a0 = ld8(hw + (size_t)(0 * 32 + mf * 16 + l15) * 128 + lg * 8 + kc);
      u16x8 a1 = ld8(hw + (size_t)(1 * 32 + mf * 16 + l15) * 128 + lg * 8 + kc);
      u16x8 a2 = ld8(hw + (size_t)(2 * 32 + mf * 16 + l15) * 128 + lg * 8 + kc);
      acc[0][mf] = mfma16(a0, vs, acc[0][mf]);
      acc[1][mf] = mfma16(a1, vp, acc[1][mf]);
      acc[2][mf] = mfma16(a2, vc, acc[2][mf]);
    }
  }
  const float* bias[3] = {clsb, apb, acb};
  const size_t hoff[3] = {0, 311296, 622592};
#pragma unroll
  for (int hd = 0; hd < 3; ++hd)
#pragma unroll
    for (int mf = 0; mf < 2; ++mf)
#pragma unroll
      for (int r = 0; r < 4; ++r) {
        int co = mf * 16 + lg * 4 + r;
        if (co < 19)
          out[hoff[hd] + ((size_t)b * 19 + co) * 4096 + n] = acc[hd][mf][r] + bias[hd][co];
      }
}

// ---------------------------------------------------------------------------
extern "C" void kernel_launch(void* const* d_in, const int* in_sizes, int n_in,
                              void* d_out, int out_size, void* d_ws, size_t ws_size,
                              hipStream_t stream) {
  (void)in_sizes; (void)n_in; (void)out_size; (void)ws_size;
  const float* x = (const float*)d_in[0];
  const float* wp1 = (const float*)d_in[1];
  const float* g1p = (const float*)d_in[2];
  const float* b1p = (const float*)d_in[3];
  const float* m1p = (const float*)d_in[4];
  const float* v1p = (const float*)d_in[5];
  const float* qw = (const float*)d_in[6];
  const float* qb = (const float*)d_in[7];
  const float* kw = (const float*)d_in[8];
  const float* kb = (const float*)d_in[9];
  const float* vw = (const float*)d_in[10];
  const float* vb = (const float*)d_in[11];
  const float* pamg = (const float*)d_in[12];
  const float* wp2 = (const float*)d_in[13];
  const float* g2p = (const float*)d_in[14];
  const float* b2p = (const float*)d_in[15];
  const float* m2p = (const float*)d_in[16];
  const float* v2p = (const float*)d_in[17];
  const float* wc1 = (const float*)d_in[18];
  const float* g1c = (const float*)d_in[19];
  const float* b1c = (const float*)d_in[20];
  const float* m1c = (const float*)d_in[21];
  const float* v1c = (const float*)d_in[22];
  const float* camg = (const float*)d_in[23];
  const float* wc2 = (const float*)d_in[24];
  const float* g2c = (const float*)d_in[25];
  const float* b2c = (const float*)d_in[26];
  const float* m2c = (const float*)d_in[27];
  const float* v2c = (const float*)d_in[28];
  const float* clsw = (const float*)d_in[29];
  const float* clsb = (const float*)d_in[30];
  const float* apw = (const float*)d_in[31];
  const float* apb = (const float*)d_in[32];
  const float* acw = (const float*)d_in[33];
  const float* acb = (const float*)d_in[34];

  char* ws = (char*)d_ws;
  unsigned short* xt = (unsigned short*)(ws + OFF_XT);
  unsigned short* fp1 = (unsigned short*)(ws + OFF_FP1);
  unsigned short* fc1 = (unsigned short*)(ws + OFF_FC1);
  unsigned short* fp0 = (unsigned short*)(ws + OFF_FP0);
  unsigned short* fc0 = (unsigned short*)(ws + OFF_FC0);
  unsigned short* fp2 = (unsigned short*)(ws + OFF_FP2);
  unsigned short* fc2 = (unsigned short*)(ws + OFF_FC2);
  unsigned short* wt1 = (unsigned short*)(ws + OFF_WT1);
  unsigned short* wt2 = (unsigned short*)(ws + OFF_WT2);
  unsigned short* qkw = (unsigned short*)(ws + OFF_QKW);
  unsigned short* vww = (unsigned short*)(ws + OFF_VWW);
  unsigned short* hww = (unsigned short*)(ws + OFF_HWW);
  float* bnss = (float*)(ws + OFF_BNSS);
  unsigned short* Qb = (unsigned short*)(ws + OFF_Q);
  unsigned short* Kb = (unsigned short*)(ws + OFF_K);
  unsigned short* Vb = (unsigned short*)(ws + OFF_V);
  unsigned short* attnb = (unsigned short*)(ws + OFF_ATTN);
  float* Gp = (float*)(ws + OFF_XT);  // alias: xt dead after conv1

  // zero chunked (padded) buffers: xt + fp1 + fc1
  hipMemsetAsync(ws, 0, ZERO_BYTES, stream);

  PackArgs pa;
  pa.wp1 = wp1; pa.wc1 = wc1; pa.wp2 = wp2; pa.wc2 = wc2;
  pa.qw = qw; pa.kw = kw; pa.vw = vw; pa.clsw = clsw; pa.apw = apw; pa.acw = acw;
  pa.g1p = g1p; pa.b1p = b1p; pa.m1p = m1p; pa.v1p = v1p;
  pa.g1c = g1c; pa.b1c = b1c; pa.m1c = m1c; pa.v1c = v1c;
  pa.g2p = g2p; pa.b2p = b2p; pa.m2p = m2p; pa.v2p = v2p;
  pa.g2c = g2c; pa.b2c = b2c; pa.m2c = m2c; pa.v2c = v2c;
  pa.wt1 = wt1; pa.wt2 = wt2; pa.qkw = qkw; pa.vww = vww; pa.hww = hww; pa.bnss = bnss;
  k_pack<<<5892, 256, 0, stream>>>(pa);

  k_xpose<<<1024, 256, 0, stream>>>(x, xt);

  k_conv3x3<8><<<512, 256, 0, stream>>>(xt, xt, wt1, bnss, fp0, fc0);

  k_qkv<<<256, 256, 0, stream>>>(fp0, qkw, vww, qb, kb, vb, Qb, Kb, Vb);
  k_gram<<<256, 256, 0, stream>>>(fc0, Gp);
  k_pam<<<256, 512, 0, stream>>>(Qb, Kb, Vb, fp0, fp1, pamg);
  k_softm<<<512, 128, 0, stream>>>(Gp, attnb);
  k_camout<<<256, 256, 0, stream>>>(fc0, attnb, camg, fc1);

  k_conv3x3<2><<<512, 256, 0, stream>>>(fp1, fc1, wt2, bnss + 512, fp2, fc2);

  k_heads<<<256, 256, 0, stream>>>(fp2, fc2, hww, clsb, apb, acb, (float*)d_out);
}

// Round 8
// 198.440 us; speedup vs baseline: 1.0407x; 1.0407x over previous
//
#include <hip/hip_runtime.h>
#include <cstdint>
#include <cstddef>

// ---------------------------------------------------------------------------
// DANet dual-attention head on MI355X.
// This round: conv v4 — 128x128 block / M2N2 waves (R=1), W triple-buffered
// per tap staged TWO taps ahead with counted vmcnt(4) (never drain mid-loop),
// A window reg-prefetched 9 taps ahead.  Phase-robust XOR key (c^(c>>3))&7.
// ---------------------------------------------------------------------------

using s16x8 = __attribute__((ext_vector_type(8))) short;
using u16x8 = __attribute__((ext_vector_type(8))) unsigned short;
using u16x4 = __attribute__((ext_vector_type(4))) unsigned short;
using f32x4 = __attribute__((ext_vector_type(4))) float;
using f32x16 = __attribute__((ext_vector_type(16))) float;
using u32x4v = __attribute__((ext_vector_type(4))) unsigned;

__device__ __forceinline__ f32x4 mfma16(u16x8 a, u16x8 b, f32x4 c) {
  return __builtin_amdgcn_mfma_f32_16x16x32_bf16(
      __builtin_bit_cast(s16x8, a), __builtin_bit_cast(s16x8, b), c, 0, 0, 0);
}
__device__ __forceinline__ f32x16 mfma32(u16x8 a, u16x8 b, f32x16 c) {
  return __builtin_amdgcn_mfma_f32_32x32x16_bf16(
      __builtin_bit_cast(s16x8, a), __builtin_bit_cast(s16x8, b), c, 0, 0, 0);
}
__device__ __forceinline__ float bf2f(unsigned short u) {
  return __builtin_bit_cast(float, (unsigned)u << 16);
}
__device__ __forceinline__ unsigned short f2bf(float f) {  // RNE
  unsigned u = __builtin_bit_cast(unsigned, f);
  u += 0x7fffu + ((u >> 16) & 1u);
  return (unsigned short)(u >> 16);
}
__device__ __forceinline__ unsigned cvt_pk_bf16(float lo, float hi) {
  unsigned r;
  asm("v_cvt_pk_bf16_f32 %0, %1, %2" : "=v"(r) : "v"(lo), "v"(hi));
  return r;
}
__device__ __forceinline__ u16x8 ld8(const unsigned short* p) {
  return *reinterpret_cast<const u16x8*>(p);
}
__device__ __forceinline__ void gload16(const void* g, void* l) {
  __builtin_amdgcn_global_load_lds(
      (const __attribute__((address_space(1))) void*)g,
      (__attribute__((address_space(3))) void*)l, 16, 0, 0);
}

// ---------------- workspace layout (bytes) ----------------
#define OFF_XT    ((size_t)0)           // [4][8][66][72][64] bf16 = 19,464,192 (Gp aliases)
#define OFF_FP1   ((size_t)19464192)    // [4][2][66][72][64] bf16 = 4,866,048
#define OFF_FC1   ((size_t)24330240)
#define ZERO_BYTES ((size_t)29196288)
#define OFF_FP0   ((size_t)29196288)    // [4][4096][128] bf16 = 4,194,304 (flat)
#define OFF_FC0   ((size_t)33390592)
#define OFF_FP2   ((size_t)37584896)    // flat; Q/K alias here before conv2
#define OFF_FC2   ((size_t)41779200)    // flat; V aliases here before conv2
#define OFF_WT1   ((size_t)45973504)    // [2][8][9][128][64] bf16 = 2,359,296
#define OFF_WT2   ((size_t)48332800)    // [2][2][9][128][64] bf16 = 589,824
#define OFF_QKW   ((size_t)48922624)    // [2][16][128] bf16 = 8,192
#define OFF_VWW   ((size_t)48930816)    // [128][128] bf16 = 32,768
#define OFF_HWW   ((size_t)48963584)    // [3][32][128] bf16 = 24,576
#define OFF_BNSS  ((size_t)48988160)    // 8*128 f32 = 4,096
#define OFF_ATTN  ((size_t)48992256)    // [4][128][128] bf16 = 131,072
#define OFF_Q     OFF_FP2               // [4][4096][16] = 524,288
#define OFF_K     (OFF_FP2 + 524288)
#define OFF_V     OFF_FC2               // [4][512][128][8] m-blocked = 4,194,304

// ---------------- x: NCHW fp32 -> chunked NHWC bf16 padded (linear) -------
__global__ __launch_bounds__(256) void k_xpose(const float* __restrict__ x,
                                               unsigned short* __restrict__ xt) {
  __shared__ float tile[128][65];
  const int t = threadIdx.x;
  const int blk = blockIdx.x;  // 4b * 64h * 4cb
  const int cb = blk & 3;
  const int h = (blk >> 2) & 63;
  const int b = blk >> 8;
  const float* src = x + ((size_t)(b * 512 + cb * 128) * 64 + h) * 64;
  const int w = t & 63, cr = t >> 6;
  for (int i = 0; i < 32; ++i) tile[cr + i * 4][w] = src[(size_t)(cr + i * 4) * 4096 + w];
  __syncthreads();
  const int w2 = t >> 2, cg = t & 3;
  const int cic = cb * 2 + (cg >> 1);
  unsigned short* dst =
      xt + (((size_t)(b * 8 + cic) * 66 + h + 1) * 72 + (w2 + 1)) * 64 + (cg & 1) * 32;
#pragma unroll
  for (int j = 0; j < 32; j += 4) {
    u16x4 pk;
    pk[0] = f2bf(tile[cg * 32 + j + 0][w2]);
    pk[1] = f2bf(tile[cg * 32 + j + 1][w2]);
    pk[2] = f2bf(tile[cg * 32 + j + 2][w2]);
    pk[3] = f2bf(tile[cg * 32 + j + 3][w2]);
    *reinterpret_cast<u16x4*>(dst + j) = pk;
  }
}

// ---------------- weight / BN pre-pack ----------------
// wt layouts: [br][cic][tap][co128][ci64], ci pre-swizzled with key
// ((co ^ (co>>3)) & 7) << 3 elements (gload dest must be linear).
struct PackArgs {
  const float *wp1, *wc1, *wp2, *wc2, *qw, *kw, *vw, *clsw, *apw, *acw;
  const float *g1p, *b1p, *m1p, *v1p, *g1c, *b1c, *m1c, *v1c;
  const float *g2p, *b2p, *m2p, *v2p, *g2c, *b2c, *m2c, *v2c;
  unsigned short *wt1, *wt2, *qkw, *vww, *hww;
  float* bnss;
};
__global__ __launch_bounds__(256) void k_pack(PackArgs A) {
  const int i = blockIdx.x * 256 + threadIdx.x;
  const int N1 = 2 * 8 * 9 * 128 * 64;   // 1,179,648
  const int N2 = N1 + 2 * 2 * 9 * 128 * 64;
  const int N3 = N2 + 2 * 16 * 128;
  const int N4 = N3 + 128 * 128;
  const int N5 = N4 + 3 * 32 * 128;
  const int N6 = N5 + 8 * 128;
  if (i < N1) {  // wt1 [br][cic8][tap][co128][ci64]
    int ci = i & 63, co = (i >> 6) & 127;
    int rest = i >> 13;
    int tap = rest % 9, cc = rest / 9;
    int cic = cc & 7, brr = cc >> 3;
    const float* s = brr ? A.wc1 : A.wp1;
    int cis = ci ^ (((co ^ (co >> 3)) & 7) << 3);
    A.wt1[i] = f2bf(s[(size_t)(co * 512 + cic * 64 + cis) * 9 + tap]);
  } else if (i < N2) {  // wt2 [br][cic2][tap][co128][ci64]
    int k = i - N1;
    int ci = k & 63, co = (k >> 6) & 127;
    int rest = k >> 13;
    int tap = rest % 9, cc = rest / 9;
    int cic = cc & 1, brr = cc >> 1;
    const float* s = brr ? A.wc2 : A.wp2;
    int cis = ci ^ (((co ^ (co >> 3)) & 7) << 3);
    A.wt2[k] = f2bf(s[(size_t)(co * 128 + cic * 64 + cis) * 9 + tap]);
  } else if (i < N3) {
    int k = i - N2;
    int ci = k & 127, q = k >> 7;
    const float* s = (q < 16) ? A.qw : A.kw;
    A.qkw[k] = f2bf(s[(q & 15) * 128 + ci]);
  } else if (i < N4) {
    int k = i - N3;
    A.vww[k] = f2bf(A.vw[k]);
  } else if (i < N5) {
    int k = i - N4;
    int ci = k & 127, co = (k >> 7) & 31, hd = k >> 12;
    const float* s = hd == 0 ? A.clsw : (hd == 1 ? A.apw : A.acw);
    A.hww[k] = (co < 19) ? f2bf(s[co * 128 + ci]) : (unsigned short)0;
  } else if (i < N6) {
    int k = i - N5;
    int j = k & 127, seg = k >> 7;
    const float *g, *bb, *mm, *vv;
    switch (seg >> 1) {
      case 0: g = A.g1p; bb = A.b1p; mm = A.m1p; vv = A.v1p; break;
      case 1: g = A.g1c; bb = A.b1c; mm = A.m1c; vv = A.v1c; break;
      case 2: g = A.g2p; bb = A.b2p; mm = A.m2p; vv = A.v2p; break;
      default: g = A.g2c; bb = A.b2c; mm = A.m2c; vv = A.v2c; break;
    }
    float sc = g[j] * rsqrtf(vv[j] + 1e-5f);
    A.bnss[k] = (seg & 1) ? (bb[j] - mm[j] * sc) : sc;
  }
}

// ---------------- 3x3 conv v4: 128x128 block, deep W pipeline -------------
// 4 waves of 64n x 64co (M2N2, R=1 LDS-read/MFMA).  A window [4][72][64]
// = 36 KB (reg-prefetched 9 taps ahead, swizzle-on-write).  W per tap
// [128co][64ci] = 16 KB, TRIPLE buffered, staged 2 taps ahead via
// global_load_lds; end-of-tap wait = vmcnt(4) (one stage always in flight).
template <int NCHUNK>
__global__ __launch_bounds__(256, 1) void k_conv3x3(
    const unsigned short* __restrict__ in0, const unsigned short* __restrict__ in1,
    const unsigned short* __restrict__ wt, const float* __restrict__ bnb,
    unsigned short* __restrict__ out0, unsigned short* __restrict__ out1) {
  __shared__ unsigned short Awin[4 * 72 * 64];  // 36 KB
  __shared__ unsigned short Wbuf[3][128 * 64];  // 3 x 16 KB
  const int bid = blockIdx.x;
  const int ht = bid & 31;
  const int b = (bid >> 5) & 3;
  const int br = bid >> 7;
  const unsigned short* inp = br ? in1 : in0;
  const unsigned short* wbr = wt + (size_t)br * NCHUNK * 9 * 128 * 64;
  const float* scale = bnb + br * 256;
  const float* shiftp = scale + 128;
  unsigned short* outp = br ? out1 : out0;
  const int tid = threadIdx.x;
  const int lane = tid & 63, wv = tid >> 6;
  const int l31 = lane & 31, hi = lane >> 5;
  const int hi16 = hi * 16;
  const int wn = (wv & 1) * 64, cob = (wv >> 1) * 64;
  const int h0 = ht * 2;

  int agrp[2], aw[2];
#pragma unroll
  for (int mf = 0; mf < 2; ++mf) {
    int n = wn + mf * 32 + l31;
    aw[mf] = n & 63;
    agrp[mf] = (n >> 6) * 72;
  }
  int bbase[2], bkey[2];
#pragma unroll
  for (int nf = 0; nf < 2; ++nf) {
    int co = cob + nf * 32 + l31;
    bbase[nf] = co * 128;
    bkey[nf] = ((co ^ (co >> 3)) & 7) << 4;
  }

  f32x16 acc[2][2];
#pragma unroll
  for (int mf = 0; mf < 2; ++mf)
#pragma unroll
    for (int nf = 0; nf < 2; ++nf) acc[mf][nf] = (f32x16)0.f;

  u16x8 streg[9];
  auto sloadA = [&](int c) {  // window rows h0..h0+3, linear global -> regs
    const char* sr =
        (const char*)(inp + (((size_t)(b * NCHUNK + c) * 66 + h0) * 72) * 64);
#pragma unroll
    for (int i = 0; i < 9; ++i)
      streg[i] = *(const u16x8*)(sr + i * 4096 + tid * 16);
  };
  auto swriteA = [&]() {  // regs -> LDS, swizzle applied at write
    char* dp = (char*)Awin;
#pragma unroll
    for (int i = 0; i < 9; ++i) {
      int g = i * 32 + (tid >> 3);  // 128B group 0..287
      int row = g / 72;
      int col = g - row * 72;
      int key = ((col ^ (col >> 3)) & 7) << 4;
      *(u16x8*)(dp + g * 128 + (((tid & 7) * 16) ^ key)) = streg[i];
    }
  };
  auto stageW = [&](int bi, int T) {  // 16 KB linear copy (pre-swz global)
    const char* src = (const char*)wbr + (size_t)T * 16384;
    char* dst = (char*)&Wbuf[bi][0];
#pragma unroll
    for (int i = 0; i < 4; ++i)
      gload16(src + i * 4096 + tid * 16, dst + i * 4096 + tid * 16);
  };
  auto compute_tap = [&](int ty, int tx, int bi) {
    const char* ab = (const char*)Awin;
    const char* wb = (const char*)&Wbuf[bi][0];
    int abase[2], akey[2];
#pragma unroll
    for (int mf = 0; mf < 2; ++mf) {
      int wc = aw[mf] + tx;
      abase[mf] = (agrp[mf] + ty * 72 + wc) << 7;
      akey[mf] = ((wc ^ (wc >> 3)) & 7) << 4;
    }
#pragma unroll
    for (int s = 0; s < 4; ++s) {
      const int ko = s * 32 + hi16;
      u16x8 av[2], bv[2];
#pragma unroll
      for (int mf = 0; mf < 2; ++mf)
        av[mf] = *(const u16x8*)(ab + abase[mf] + (ko ^ akey[mf]));
#pragma unroll
      for (int nf = 0; nf < 2; ++nf)
        bv[nf] = *(const u16x8*)(wb + bbase[nf] + (ko ^ bkey[nf]));
#pragma unroll
      for (int mf = 0; mf < 2; ++mf)
#pragma unroll
        for (int nf = 0; nf < 2; ++nf)
          acc[mf][nf] = mfma32(av[mf], bv[nf], acc[mf][nf]);
    }
  };

  const int total = 9 * NCHUNK;
  // prologue
  sloadA(0);
  swriteA();  // compiler inserts vmcnt wait for streg
  stageW(0, 0);
  stageW(1, 1);
  asm volatile("s_waitcnt vmcnt(4) lgkmcnt(0)" ::: "memory");
  __builtin_amdgcn_s_barrier();

#pragma unroll 1
  for (int c = 0; c < NCHUNK; ++c) {
    const bool pf = (c + 1 < NCHUNK);
#pragma unroll
    for (int t = 0; t < 9; ++t) {
      const int T = c * 9 + t;
      if (T + 2 < total) stageW((T + 2) % 3, T + 2);
      if (t == 0 && pf) sloadA(c + 1);
      compute_tap(t / 3, t - (t / 3) * 3, T % 3);
      if (T + 1 == total) break;  // last tap
      if (t == 8) {
        // chunk boundary: drain reads of Awin, rewrite, resync
        asm volatile("s_waitcnt lgkmcnt(0)" ::: "memory");
        __builtin_amdgcn_s_barrier();
        swriteA();  // streg landed long ago (compiler-checked)
        asm volatile("s_waitcnt vmcnt(4) lgkmcnt(0)" ::: "memory");
        __builtin_amdgcn_s_barrier();
      } else if (pf && t < 2) {
        // A-prefetch (9 loads) still outstanding behind W stages
        asm volatile("s_waitcnt vmcnt(13) lgkmcnt(0)" ::: "memory");
        __builtin_amdgcn_s_barrier();
      } else if (T + 2 < total) {
        asm volatile("s_waitcnt vmcnt(4) lgkmcnt(0)" ::: "memory");
        __builtin_amdgcn_s_barrier();
      } else {
        asm volatile("s_waitcnt vmcnt(0) lgkmcnt(0)" ::: "memory");
        __builtin_amdgcn_s_barrier();
      }
    }
  }

  // epilogue: BN + ReLU + flat NHWC store (32x32 D layout)
#pragma unroll
  for (int nf = 0; nf < 2; ++nf) {
    const int co = cob + nf * 32 + l31;
    const float sc = scale[co], sh = shiftp[co];
#pragma unroll
    for (int mf = 0; mf < 2; ++mf)
#pragma unroll
      for (int r = 0; r < 16; ++r) {
        int n = wn + mf * 32 + (r & 3) + 8 * (r >> 2) + 4 * hi;
        float y = acc[mf][nf][r] * sc + sh;
        y = y > 0.f ? y : 0.f;
        outp[((size_t)b * 4096 + (size_t)(h0 + (n >> 6)) * 64 + (n & 63)) * 128 + co] =
            f2bf(y);
      }
  }
}

// ---------------- PAM Q/K/V 1x1 projections (MFMA) ----------------
__global__ __launch_bounds__(256) void k_qkv(
    const unsigned short* __restrict__ fp0, const unsigned short* __restrict__ qkw,
    const unsigned short* __restrict__ vww, const float* __restrict__ qb,
    const float* __restrict__ kb, const float* __restrict__ vb,
    unsigned short* __restrict__ Q, unsigned short* __restrict__ K,
    unsigned short* __restrict__ V2) {
  const int bid = blockIdx.x;
  const int nt = bid & 63, b = bid >> 6;
  const int lane = threadIdx.x & 63, wv = threadIdx.x >> 6;
  const int lg = lane >> 4, l15 = lane & 15;
  const int n = nt * 64 + wv * 16 + l15;
  const unsigned short* fbase = fp0 + ((size_t)b * 4096 + n) * 128 + lg * 8;
  f32x4 vacc[8];
#pragma unroll
  for (int mf = 0; mf < 8; ++mf) vacc[mf] = (f32x4){0.f, 0.f, 0.f, 0.f};
  f32x4 qacc = {0.f, 0.f, 0.f, 0.f}, kacc = {0.f, 0.f, 0.f, 0.f};
#pragma unroll
  for (int kc = 0; kc < 128; kc += 32) {
    u16x8 fb = ld8(fbase + kc);
    u16x8 qa = ld8(qkw + (size_t)l15 * 128 + lg * 8 + kc);
    u16x8 ka = ld8(qkw + 2048 + (size_t)l15 * 128 + lg * 8 + kc);
    qacc = mfma16(qa, fb, qacc);
    kacc = mfma16(ka, fb, kacc);
#pragma unroll
    for (int mf = 0; mf < 8; ++mf) {
      u16x8 va = ld8(vww + (size_t)(mf * 16 + l15) * 128 + lg * 8 + kc);
      vacc[mf] = mfma16(va, fb, vacc[mf]);
    }
  }
  const float LOG2E = 1.44269504088896f;
#pragma unroll
  for (int r = 0; r < 4; ++r) {
    int cq = lg * 4 + r;
    Q[(size_t)(b * 4096 + n) * 16 + cq] = f2bf((qacc[r] + qb[cq]) * LOG2E);
    K[(size_t)(b * 4096 + n) * 16 + cq] = f2bf(kacc[r] + kb[cq]);
  }
#pragma unroll
  for (int mf = 0; mf < 8; ++mf)
#pragma unroll
    for (int r = 0; r < 4; ++r) {
      int c = mf * 16 + lg * 4 + r;
      V2[((size_t)(b * 512 + (n >> 3)) * 128 + c) * 8 + (n & 7)] =
          f2bf(vacc[mf][r] + vb[c]);
    }
}

// ---------------- PAM attention: split-m, register-only body --------------
__global__ __launch_bounds__(512, 1) void k_pam(
    const unsigned short* __restrict__ Q, const unsigned short* __restrict__ K,
    const unsigned short* __restrict__ V2, const unsigned short* __restrict__ fp0,
    unsigned short* __restrict__ fp1, const float* __restrict__ pg) {
  __shared__ float obuf[2][3][16][64][4];  // 96 KB partial-O
  __shared__ float lred[8][64];            // denom partials
  const int bid = blockIdx.x;  // 4b * 64qt
  const int qt = bid & 63, b = bid >> 6;
  const int tid = threadIdx.x;
  const int lane = tid & 63, wv = tid >> 6;
  const int qsub = wv >> 2, mq = wv & 3;
  const int l31 = lane & 31, hi = lane >> 5;
  const int q0 = qt * 64 + qsub * 32;
  const unsigned short* Qp = Q + (size_t)b * 65536;
  const unsigned short* Kp = K + (size_t)b * 65536;
  const unsigned short* Vp = V2 + (size_t)b * 524288;
  const int hi8 = hi * 8;

  const u16x8 qB = ld8(Qp + (size_t)(q0 + l31) * 16 + hi8);

  f32x16 oacc[4];
#pragma unroll
  for (int ch = 0; ch < 4; ++ch) oacc[ch] = (f32x16)0.f;
  float dsum = 0.f;

  auto loadK = [&](int t) -> u16x8 {
    return ld8(Kp + (size_t)(t * 32 + l31) * 16 + hi8);
  };
  auto loadV = [&](int t, u16x8 (&vf)[8]) {
#pragma unroll
    for (int kc = 0; kc < 2; ++kc)
#pragma unroll
      for (int ch = 0; ch < 4; ++ch)
        vf[kc * 4 + ch] =
            ld8(Vp + (size_t)(t * 4 + kc * 2 + hi) * 1024 + (ch * 32 + l31) * 8);
  };
  auto body = [&](u16x8 kA, u16x8 (&vf)[8]) {
    f32x16 pacc = mfma32(kA, qB, (f32x16)0.f);
    float p[16];
#pragma unroll
    for (int r = 0; r < 16; ++r) p[r] = exp2f(pacc[r]);
    dsum += (((p[0] + p[1]) + (p[2] + p[3])) + ((p[4] + p[5]) + (p[6] + p[7]))) +
            (((p[8] + p[9]) + (p[10] + p[11])) + ((p[12] + p[13]) + (p[14] + p[15])));
    unsigned X[8], S[8];
#pragma unroll
    for (int j = 0; j < 8; ++j) X[j] = cvt_pk_bf16(p[2 * j], p[2 * j + 1]);
#pragma unroll
    for (int j = 0; j < 8; ++j) S[j] = __shfl_xor(X[j], 32, 64);
    const bool hc = hi != 0;
    u32x4v w0, w1;
    w0[0] = hc ? S[2] : X[0];
    w0[1] = hc ? S[3] : X[1];
    w0[2] = hc ? X[2] : S[0];
    w0[3] = hc ? X[3] : S[1];
    w1[0] = hc ? S[6] : X[4];
    w1[1] = hc ? S[7] : X[5];
    w1[2] = hc ? X[6] : S[4];
    w1[3] = hc ? X[7] : S[5];
    u16x8 f0 = __builtin_bit_cast(u16x8, w0);
    u16x8 f1 = __builtin_bit_cast(u16x8, w1);
#pragma unroll
    for (int ch = 0; ch < 4; ++ch) oacc[ch] = mfma32(f0, vf[ch], oacc[ch]);
#pragma unroll
    for (int ch = 0; ch < 4; ++ch) oacc[ch] = mfma32(f1, vf[4 + ch], oacc[ch]);
  };

  const int t0 = mq * 32;
  u16x8 kA0 = loadK(t0), kA1;
  u16x8 vf0[8], vf1[8];
  loadV(t0, vf0);
#pragma unroll 1
  for (int t = 0; t < 32; t += 2) {
    kA1 = loadK(t0 + t + 1);
    loadV(t0 + t + 1, vf1);
    body(kA0, vf0);
    if (t + 2 < 32) {
      kA0 = loadK(t0 + t + 2);
      loadV(t0 + t + 2, vf0);
    }
    body(kA1, vf1);
  }

  dsum += __shfl_xor(dsum, 32, 64);
  lred[wv][lane] = dsum;
  if (mq) {
#pragma unroll
    for (int ch = 0; ch < 4; ++ch)
#pragma unroll
      for (int j = 0; j < 4; ++j) {
        f32x4 v = {oacc[ch][4 * j + 0], oacc[ch][4 * j + 1], oacc[ch][4 * j + 2],
                   oacc[ch][4 * j + 3]};
        *reinterpret_cast<f32x4*>(&obuf[qsub][mq - 1][ch * 4 + j][lane][0]) = v;
      }
  }
  __syncthreads();
  if (mq == 0) {
    const float dtot = lred[qsub * 4 + 0][lane] + lred[qsub * 4 + 1][lane] +
                       lred[qsub * 4 + 2][lane] + lred[qsub * 4 + 3][lane];
#pragma unroll
    for (int ch = 0; ch < 4; ++ch)
#pragma unroll
      for (int j = 0; j < 4; ++j) {
        f32x4 s0 = *reinterpret_cast<const f32x4*>(&obuf[qsub][0][ch * 4 + j][lane][0]);
        f32x4 s1 = *reinterpret_cast<const f32x4*>(&obuf[qsub][1][ch * 4 + j][lane][0]);
        f32x4 s2 = *reinterpret_cast<const f32x4*>(&obuf[qsub][2][ch * 4 + j][lane][0]);
#pragma unroll
        for (int r = 0; r < 4; ++r)
          oacc[ch][4 * j + r] += (s0[r] + s1[r]) + s2[r];
      }
    const float rden = 1.f / dtot;
    const float gm = pg[0];
    float rdr[16];
#pragma unroll
    for (int r = 0; r < 16; ++r)
      rdr[r] = __shfl(rden, (r & 3) + 8 * (r >> 2) + 4 * hi, 64);
#pragma unroll
    for (int ch = 0; ch < 4; ++ch) {
      const int c = ch * 32 + l31;
#pragma unroll
      for (int r = 0; r < 16; ++r) {
        const int n = q0 + (r & 3) + 8 * (r >> 2) + 4 * hi;
        float o = gm * oacc[ch][r] * rdr[r] +
                  bf2f(fp0[((size_t)b * 4096 + n) * 128 + c]);
        fp1[(((size_t)(b * 2 + (c >> 6)) * 66 + (n >> 6) + 1) * 72 + ((n & 63) + 1)) *
                64 +
            (c & 63)] = f2bf(o);
      }
    }
  }
}

// ---------------- CAM Gram partials (fp32 VALU) ----------------
__global__ __launch_bounds__(256) void k_gram(const unsigned short* __restrict__ fc0,
                                              float* __restrict__ Gp) {
  __shared__ float fl[32][132];
  const int bid = blockIdx.x;
  const int nc = bid & 63, b = bid >> 6;
  const int t = threadIdx.x;
  const int i = t >> 1, jh = (t & 1) * 64;
  float acc[64];
#pragma unroll
  for (int j = 0; j < 64; ++j) acc[j] = 0.f;
  for (int c2 = 0; c2 < 2; ++c2) {
    const int n0 = nc * 64 + c2 * 32;
    {
      int nn = t >> 3, kh = t & 7;
      const unsigned short* src = fc0 + ((size_t)b * 4096 + n0 + nn) * 128 + kh * 16;
      u16x8 v0 = ld8(src), v1 = ld8(src + 8);
#pragma unroll
      for (int e = 0; e < 8; ++e) {
        fl[nn][kh * 16 + e] = bf2f(v0[e]);
        fl[nn][kh * 16 + 8 + e] = bf2f(v1[e]);
      }
    }
    __syncthreads();
    for (int nn = 0; nn < 32; ++nn) {
      float fi = fl[nn][i];
      const float4* row = reinterpret_cast<const float4*>(&fl[nn][jh]);
#pragma unroll
      for (int j4 = 0; j4 < 16; ++j4) {
        float4 fv = row[j4];
        acc[4 * j4 + 0] += fi * fv.x;
        acc[4 * j4 + 1] += fi * fv.y;
        acc[4 * j4 + 2] += fi * fv.z;
        acc[4 * j4 + 3] += fi * fv.w;
      }
    }
    __syncthreads();
  }
  float* dst = Gp + (((size_t)b * 64 + nc) * 128 + i) * 128 + jh;
  float4* dst4 = reinterpret_cast<float4*>(dst);
#pragma unroll
  for (int j4 = 0; j4 < 16; ++j4)
    dst4[j4] = make_float4(acc[4 * j4], acc[4 * j4 + 1], acc[4 * j4 + 2], acc[4 * j4 + 3]);
}

// ---------------- CAM reduce + softmax (fp32) ----------------
__global__ __launch_bounds__(128) void k_softm(const float* __restrict__ Gp,
                                               unsigned short* __restrict__ attn) {
  const int bid = blockIdx.x;
  const int i = bid & 127, b = bid >> 7;
  const int j = threadIdx.x;
  float g = 0.f;
  for (int nc = 0; nc < 64; ++nc) g += Gp[(((size_t)b * 64 + nc) * 128 + i) * 128 + j];
  __shared__ float red[2], red2[2];
  float m = g;
  m = fmaxf(m, __shfl_xor(m, 1, 64));
  m = fmaxf(m, __shfl_xor(m, 2, 64));
  m = fmaxf(m, __shfl_xor(m, 4, 64));
  m = fmaxf(m, __shfl_xor(m, 8, 64));
  m = fmaxf(m, __shfl_xor(m, 16, 64));
  m = fmaxf(m, __shfl_xor(m, 32, 64));
  const int wvi = j >> 6;
  if ((j & 63) == 0) red[wvi] = m;
  __syncthreads();
  m = fmaxf(red[0], red[1]);
  float e = __expf(g - m);
  float s = e;
  s += __shfl_xor(s, 1, 64);
  s += __shfl_xor(s, 2, 64);
  s += __shfl_xor(s, 4, 64);
  s += __shfl_xor(s, 8, 64);
  s += __shfl_xor(s, 16, 64);
  s += __shfl_xor(s, 32, 64);
  if ((j & 63) == 0) red2[wvi] = s;
  __syncthreads();
  s = red2[0] + red2[1];
  attn[((size_t)b * 128 + i) * 128 + j] = f2bf(e / s);
}

// ---------------- CAM out: attn @ f, residual (MFMA) ----------------
__global__ __launch_bounds__(256) void k_camout(
    const unsigned short* __restrict__ fc0, const unsigned short* __restrict__ attn,
    const float* __restrict__ cg, unsigned short* __restrict__ fc1) {
  const int bid = blockIdx.x;
  const int nt = bid & 63, b = bid >> 6;
  const int lane = threadIdx.x & 63, wv = threadIdx.x >> 6;
  const int lg = lane >> 4, l15 = lane & 15;
  const int n = nt * 64 + wv * 16 + l15;
  const unsigned short* fbase = fc0 + ((size_t)b * 4096 + n) * 128 + lg * 8;
  const unsigned short* abase = attn + (size_t)b * 16384 + lg * 8;
  f32x4 acc[8];
#pragma unroll
  for (int mf = 0; mf < 8; ++mf) acc[mf] = (f32x4){0.f, 0.f, 0.f, 0.f};
#pragma unroll
  for (int kc = 0; kc < 128; kc += 32) {
    u16x8 fb = ld8(fbase + kc);
#pragma unroll
    for (int mf = 0; mf < 8; ++mf) {
      u16x8 aa = ld8(abase + (size_t)(mf * 16 + l15) * 128 + kc);
      acc[mf] = mfma16(aa, fb, acc[mf]);
    }
  }
  const float gm = cg[0];
  const int nn = nt * 64 + wv * 16 + l15;
#pragma unroll
  for (int mf = 0; mf < 8; ++mf)
#pragma unroll
    for (int r = 0; r < 4; ++r) {
      int c = mf * 16 + lg * 4 + r;
      float o = gm * acc[mf][r] + bf2f(fc0[((size_t)b * 4096 + nn) * 128 + c]);
      fc1[(((size_t)(b * 2 + (c >> 6)) * 66 + (nn >> 6) + 1) * 72 + (nn & 63) + 1) * 64 +
          (c & 63)] = f2bf(o);
    }
}

// ---------------- classifier heads (MFMA, fp32 out) ----------------
__global__ __launch_bounds__(256) void k_heads(
    const unsigned short* __restrict__ fp2, const unsigned short* __restrict__ fc2,
    const unsigned short* __restrict__ hw, const float* __restrict__ clsb,
    const float* __restrict__ apb, const float* __restrict__ acb,
    float* __restrict__ out) {
  const int bid = blockIdx.x;
  const int nt = bid & 63, b = bid >> 6;
  const int lane = threadIdx.x & 63, wv = threadIdx.x >> 6;
  const int lg = lane >> 4, l15 = lane & 15;
  const int n = nt * 64 + wv * 16 + l15;
  const unsigned short* pb = fp2 + (size_t)(b * 4096 + n) * 128 + lg * 8;
  const unsigned short* cb = fc2 + (size_t)(b * 4096 + n) * 128 + lg * 8;
  f32x4 acc[3][2];
#pragma unroll
  for (int hd = 0; hd < 3; ++hd)
#pragma unroll
    for (int mf = 0; mf < 2; ++mf) acc[hd][mf] = (f32x4){0.f, 0.f, 0.f, 0.f};
#pragma unroll
  for (int kc = 0; kc < 128; kc += 32) {
    u16x8 vp = ld8(pb + kc);
    u16x8 vc = ld8(cb + kc);
    u16x8 vs;
#pragma unroll
    for (int e = 0; e < 8; ++e) vs[e] = f2bf(bf2f(vp[e]) + bf2f(vc[e]));
#pragma unroll
    for (int mf = 0; mf < 2; ++mf) {
      u16x8 a0 = ld8(hw + (size_t)(0 * 32 + mf * 16 + l15) * 128 + lg * 8 + kc);
      u16x8 a1 = ld8(hw + (size_t)(1 * 32 + mf * 16 + l15) * 128 + lg * 8 + kc);
      u16x8 a2 = ld8(hw + (size_t)(2 * 32 + mf * 16 + l15) * 128 + lg * 8 + kc);
      acc[0][mf] = mfma16(a0, vs, acc[0][mf]);
      acc[1][mf] = mfma16(a1, vp, acc[1][mf]);
      acc[2][mf] = mfma16(a2, vc, acc[2][mf]);
    }
  }
  const float* bias[3] = {clsb, apb, acb};
  const size_t hoff[3] = {0, 311296, 622592};
#pragma unroll
  for (int hd = 0; hd < 3; ++hd)
#pragma unroll
    for (int mf = 0; mf < 2; ++mf)
#pragma unroll
      for (int r = 0; r < 4; ++r) {
        int co = mf * 16 + lg * 4 + r;
        if (co < 19)
          out[hoff[hd] + ((size_t)b * 19 + co) * 4096 + n] = acc[hd][mf][r] + bias[hd][co];
      }
}

// ---------------------------------------------------------------------------
extern "C" void kernel_launch(void* const* d_in, const int* in_sizes, int n_in,
                              void* d_out, int out_size, void* d_ws, size_t ws_size,
                              hipStream_t stream) {
  (void)in_sizes; (void)n_in; (void)out_size; (void)ws_size;
  const float* x = (const float*)d_in[0];
  const float* wp1 = (const float*)d_in[1];
  const float* g1p = (const float*)d_in[2];
  const float* b1p = (const float*)d_in[3];
  const float* m1p = (const float*)d_in[4];
  const float* v1p = (const float*)d_in[5];
  const float* qw = (const float*)d_in[6];
  const float* qb = (const float*)d_in[7];
  const float* kw = (const float*)d_in[8];
  const float* kb = (const float*)d_in[9];
  const float* vw = (const float*)d_in[10];
  const float* vb = (const float*)d_in[11];
  const float* pamg = (const float*)d_in[12];
  const float* wp2 = (const float*)d_in[13];
  const float* g2p = (const float*)d_in[14];
  const float* b2p = (const float*)d_in[15];
  const float* m2p = (const float*)d_in[16];
  const float* v2p = (const float*)d_in[17];
  const float* wc1 = (const float*)d_in[18];
  const float* g1c = (const float*)d_in[19];
  const float* b1c = (const float*)d_in[20];
  const float* m1c = (const float*)d_in[21];
  const float* v1c = (const float*)d_in[22];
  const float* camg = (const float*)d_in[23];
  const float* wc2 = (const float*)d_in[24];
  const float* g2c = (const float*)d_in[25];
  const float* b2c = (const float*)d_in[26];
  const float* m2c = (const float*)d_in[27];
  const float* v2c = (const float*)d_in[28];
  const float* clsw = (const float*)d_in[29];
  const float* clsb = (const float*)d_in[30];
  const float* apw = (const float*)d_in[31];
  const float* apb = (const float*)d_in[32];
  const float* acw = (const float*)d_in[33];
  const float* acb = (const float*)d_in[34];

  char* ws = (char*)d_ws;
  unsigned short* xt = (unsigned short*)(ws + OFF_XT);
  unsigned short* fp1 = (unsigned short*)(ws + OFF_FP1);
  unsigned short* fc1 = (unsigned short*)(ws + OFF_FC1);
  unsigned short* fp0 = (unsigned short*)(ws + OFF_FP0);
  unsigned short* fc0 = (unsigned short*)(ws + OFF_FC0);
  unsigned short* fp2 = (unsigned short*)(ws + OFF_FP2);
  unsigned short* fc2 = (unsigned short*)(ws + OFF_FC2);
  unsigned short* wt1 = (unsigned short*)(ws + OFF_WT1);
  unsigned short* wt2 = (unsigned short*)(ws + OFF_WT2);
  unsigned short* qkw = (unsigned short*)(ws + OFF_QKW);
  unsigned short* vww = (unsigned short*)(ws + OFF_VWW);
  unsigned short* hww = (unsigned short*)(ws + OFF_HWW);
  float* bnss = (float*)(ws + OFF_BNSS);
  unsigned short* Qb = (unsigned short*)(ws + OFF_Q);
  unsigned short* Kb = (unsigned short*)(ws + OFF_K);
  unsigned short* Vb = (unsigned short*)(ws + OFF_V);
  unsigned short* attnb = (unsigned short*)(ws + OFF_ATTN);
  float* Gp = (float*)(ws + OFF_XT);  // alias: xt dead after conv1

  // zero chunked (padded) buffers: xt + fp1 + fc1
  hipMemsetAsync(ws, 0, ZERO_BYTES, stream);

  PackArgs pa;
  pa.wp1 = wp1; pa.wc1 = wc1; pa.wp2 = wp2; pa.wc2 = wc2;
  pa.qw = qw; pa.kw = kw; pa.vw = vw; pa.clsw = clsw; pa.apw = apw; pa.acw = acw;
  pa.g1p = g1p; pa.b1p = b1p; pa.m1p = m1p; pa.v1p = v1p;
  pa.g1c = g1c; pa.b1c = b1c; pa.m1c = m1c; pa.v1c = v1c;
  pa.g2p = g2p; pa.b2p = b2p; pa.m2p = m2p; pa.v2p = v2p;
  pa.g2c = g2c; pa.b2c = b2c; pa.m2c = m2c; pa.v2c = v2c;
  pa.wt1 = wt1; pa.wt2 = wt2; pa.qkw = qkw; pa.vww = vww; pa.hww = hww; pa.bnss = bnss;
  k_pack<<<5892, 256, 0, stream>>>(pa);

  k_xpose<<<1024, 256, 0, stream>>>(x, xt);

  k_conv3x3<8><<<256, 256, 0, stream>>>(xt, xt, wt1, bnss, fp0, fc0);

  k_qkv<<<256, 256, 0, stream>>>(fp0, qkw, vww, qb, kb, vb, Qb, Kb, Vb);
  k_gram<<<256, 256, 0, stream>>>(fc0, Gp);
  k_pam<<<256, 512, 0, stream>>>(Qb, Kb, Vb, fp0, fp1, pamg);
  k_softm<<<512, 128, 0, stream>>>(Gp, attnb);
  k_camout<<<256, 256, 0, stream>>>(fc0, attnb, camg, fc1);

  k_conv3x3<2><<<256, 256, 0, stream>>>(fp1, fc1, wt2, bnss + 512, fp2, fc2);

  k_heads<<<256, 256, 0, stream>>>(fp2, fc2, hww, clsb, apb, acb, (float*)d_out);
}

// Round 9
// 196.135 us; speedup vs baseline: 1.0529x; 1.0118x over previous
//
#include <hip/hip_runtime.h>
#include <cstdint>
#include <cstddef>

// ---------------------------------------------------------------------------
// DANet dual-attention head on MI355X.
// This round: conv v5 — W operands staged global->REGISTERS (per-wave frags,
// compiler-tracked waits, reload-after-last-use = 2-tap cover), LDS holds only
// the 36 KB A window (gload_lds + pre-swizzled globals).  Inner 9 taps run
// BARRIER-FREE; 8 waves/block = 2 waves/SIMD.
// ---------------------------------------------------------------------------

using s16x8 = __attribute__((ext_vector_type(8))) short;
using u16x8 = __attribute__((ext_vector_type(8))) unsigned short;
using u16x4 = __attribute__((ext_vector_type(4))) unsigned short;
using f32x4 = __attribute__((ext_vector_type(4))) float;
using f32x16 = __attribute__((ext_vector_type(16))) float;
using u32x4v = __attribute__((ext_vector_type(4))) unsigned;

__device__ __forceinline__ f32x4 mfma16(u16x8 a, u16x8 b, f32x4 c) {
  return __builtin_amdgcn_mfma_f32_16x16x32_bf16(
      __builtin_bit_cast(s16x8, a), __builtin_bit_cast(s16x8, b), c, 0, 0, 0);
}
__device__ __forceinline__ f32x16 mfma32(u16x8 a, u16x8 b, f32x16 c) {
  return __builtin_amdgcn_mfma_f32_32x32x16_bf16(
      __builtin_bit_cast(s16x8, a), __builtin_bit_cast(s16x8, b), c, 0, 0, 0);
}
__device__ __forceinline__ float bf2f(unsigned short u) {
  return __builtin_bit_cast(float, (unsigned)u << 16);
}
__device__ __forceinline__ unsigned short f2bf(float f) {  // RNE
  unsigned u = __builtin_bit_cast(unsigned, f);
  u += 0x7fffu + ((u >> 16) & 1u);
  return (unsigned short)(u >> 16);
}
__device__ __forceinline__ unsigned cvt_pk_bf16(float lo, float hi) {
  unsigned r;
  asm("v_cvt_pk_bf16_f32 %0, %1, %2" : "=v"(r) : "v"(lo), "v"(hi));
  return r;
}
__device__ __forceinline__ u16x8 ld8(const unsigned short* p) {
  return *reinterpret_cast<const u16x8*>(p);
}
__device__ __forceinline__ void gload16(const void* g, void* l) {
  __builtin_amdgcn_global_load_lds(
      (const __attribute__((address_space(1))) void*)g,
      (__attribute__((address_space(3))) void*)l, 16, 0, 0);
}

// ---------------- workspace layout (bytes) ----------------
#define OFF_XT    ((size_t)0)           // [4][8][66][72][64] bf16 = 19,464,192 (Gp aliases)
#define OFF_FP1   ((size_t)19464192)    // [4][2][66][72][64] bf16 = 4,866,048
#define OFF_FC1   ((size_t)24330240)
#define ZERO_BYTES ((size_t)29196288)
#define OFF_FP0   ((size_t)29196288)    // [4][4096][128] bf16 = 4,194,304 (flat)
#define OFF_FC0   ((size_t)33390592)
#define OFF_FP2   ((size_t)37584896)    // flat; Q/K alias here before conv2
#define OFF_FC2   ((size_t)41779200)    // flat; V aliases here before conv2
#define OFF_WT1   ((size_t)45973504)    // [2][8][9][8192] bf16 frag-order = 2,359,296
#define OFF_WT2   ((size_t)48332800)    // [2][2][9][8192] bf16 frag-order = 589,824
#define OFF_QKW   ((size_t)48922624)    // [2][16][128] bf16 = 8,192
#define OFF_VWW   ((size_t)48930816)    // [128][128] bf16 = 32,768
#define OFF_HWW   ((size_t)48963584)    // [3][32][128] bf16 = 24,576
#define OFF_BNSS  ((size_t)48988160)    // 8*128 f32 = 4,096
#define OFF_ATTN  ((size_t)48992256)    // [4][128][128] bf16 = 131,072
#define OFF_Q     OFF_FP2               // [4][4096][16] = 524,288
#define OFF_K     (OFF_FP2 + 524288)
#define OFF_V     OFF_FC2               // [4][512][128][8] m-blocked = 4,194,304

__device__ __forceinline__ int swzkey8(int col) {  // element-unit XOR key
  return ((col ^ (col >> 3)) & 7) << 3;
}

// ---------------- x: NCHW fp32 -> chunked NHWC bf16 padded, PRE-SWIZZLED --
// Global position p within each 64-ci group holds element p ^ key8(col).
__global__ __launch_bounds__(256) void k_xpose(const float* __restrict__ x,
                                               unsigned short* __restrict__ xt) {
  __shared__ float tile[128][65];
  const int t = threadIdx.x;
  const int blk = blockIdx.x;  // 4b * 64h * 4cb
  const int cb = blk & 3;
  const int h = (blk >> 2) & 63;
  const int b = blk >> 8;
  const float* src = x + ((size_t)(b * 512 + cb * 128) * 64 + h) * 64;
  const int w = t & 63, cr = t >> 6;
  for (int i = 0; i < 32; ++i) tile[cr + i * 4][w] = src[(size_t)(cr + i * 4) * 4096 + w];
  __syncthreads();
  const int w2 = t >> 2, cg = t & 3;
  const int cic = cb * 2 + (cg >> 1);
  const int col = w2 + 1;
  const int key8 = swzkey8(col);
  unsigned short* dst =
      xt + (((size_t)(b * 8 + cic) * 66 + h + 1) * 72 + col) * 64 + (cg & 1) * 32;
#pragma unroll
  for (int j = 0; j < 32; j += 4) {
    const int q0 = (cg & 1) * 32 + j;               // position in 64-group
    const int srow = (cg >> 1) * 64 + (q0 ^ key8);  // source channel
    u16x4 pk;
    pk[0] = f2bf(tile[srow + 0][w2]);
    pk[1] = f2bf(tile[srow + 1][w2]);
    pk[2] = f2bf(tile[srow + 2][w2]);
    pk[3] = f2bf(tile[srow + 3][w2]);
    *reinterpret_cast<u16x4*>(dst + j) = pk;
  }
}

// ---------------- weight / BN pre-pack ----------------
// wt layouts: [br][cic][tap][q=cg*4+s][lane=hi*32+l31][e], co=cg*32+l31,
// ci=s*16+hi*8+e  -> conv W reg-loads are 16B/lane coalesced, no swizzle.
struct PackArgs {
  const float *wp1, *wc1, *wp2, *wc2, *qw, *kw, *vw, *clsw, *apw, *acw;
  const float *g1p, *b1p, *m1p, *v1p, *g1c, *b1c, *m1c, *v1c;
  const float *g2p, *b2p, *m2p, *v2p, *g2c, *b2c, *m2c, *v2c;
  unsigned short *wt1, *wt2, *qkw, *vww, *hww;
  float* bnss;
};
__global__ __launch_bounds__(256) void k_pack(PackArgs A) {
  const int i = blockIdx.x * 256 + threadIdx.x;
  const int N1 = 2 * 8 * 9 * 8192;   // 1,179,648
  const int N2 = N1 + 2 * 2 * 9 * 8192;
  const int N3 = N2 + 2 * 16 * 128;
  const int N4 = N3 + 128 * 128;
  const int N5 = N4 + 3 * 32 * 128;
  const int N6 = N5 + 8 * 128;
  if (i < N1) {  // wt1
    int e = i & 7, ln = (i >> 3) & 63, q = (i >> 9) & 15;
    int rest = i >> 13;
    int tap = rest % 9, cc = rest / 9;
    int cic = cc & 7, brr = cc >> 3;
    const float* s = brr ? A.wc1 : A.wp1;
    int co = (q >> 2) * 32 + (ln & 31);
    int ci = (q & 3) * 16 + (ln >> 5) * 8 + e;
    A.wt1[i] = f2bf(s[(size_t)(co * 512 + cic * 64 + ci) * 9 + tap]);
  } else if (i < N2) {  // wt2
    int k = i - N1;
    int e = k & 7, ln = (k >> 3) & 63, q = (k >> 9) & 15;
    int rest = k >> 13;
    int tap = rest % 9, cc = rest / 9;
    int cic = cc & 1, brr = cc >> 1;
    const float* s = brr ? A.wc2 : A.wp2;
    int co = (q >> 2) * 32 + (ln & 31);
    int ci = (q & 3) * 16 + (ln >> 5) * 8 + e;
    A.wt2[k] = f2bf(s[(size_t)(co * 128 + cic * 64 + ci) * 9 + tap]);
  } else if (i < N3) {
    int k = i - N2;
    int ci = k & 127, q = k >> 7;
    const float* s = (q < 16) ? A.qw : A.kw;
    A.qkw[k] = f2bf(s[(q & 15) * 128 + ci]);
  } else if (i < N4) {
    int k = i - N3;
    A.vww[k] = f2bf(A.vw[k]);
  } else if (i < N5) {
    int k = i - N4;
    int ci = k & 127, co = (k >> 7) & 31, hd = k >> 12;
    const float* s = hd == 0 ? A.clsw : (hd == 1 ? A.apw : A.acw);
    A.hww[k] = (co < 19) ? f2bf(s[co * 128 + ci]) : (unsigned short)0;
  } else if (i < N6) {
    int k = i - N5;
    int j = k & 127, seg = k >> 7;
    const float *g, *bb, *mm, *vv;
    switch (seg >> 1) {
      case 0: g = A.g1p; bb = A.b1p; mm = A.m1p; vv = A.v1p; break;
      case 1: g = A.g1c; bb = A.b1c; mm = A.m1c; vv = A.v1c; break;
      case 2: g = A.g2p; bb = A.b2p; mm = A.m2p; vv = A.v2p; break;
      default: g = A.g2c; bb = A.b2c; mm = A.m2c; vv = A.v2c; break;
    }
    float sc = g[j] * rsqrtf(vv[j] + 1e-5f);
    A.bnss[k] = (seg & 1) ? (bb[j] - mm[j] * sc) : sc;
  }
}

// ---------------- 3x3 conv v5: W in registers, barrier-free taps ----------
// 8 waves (512 thr), wave = 64n x 32co (M2N1).  A window [4][72][64] = 36 KB
// via gload_lds (pre-swizzled global).  W frags double-buffered in VGPRs,
// each frag reloaded for tap T+2 right after its last use at tap T.
template <int NCHUNK>
__global__ __launch_bounds__(512, 2) void k_conv3x3(
    const unsigned short* __restrict__ in0, const unsigned short* __restrict__ in1,
    const unsigned short* __restrict__ wt, const float* __restrict__ bnb,
    unsigned short* __restrict__ out0, unsigned short* __restrict__ out1) {
  __shared__ unsigned short Awin[4 * 72 * 64];  // 36 KB
  const int bid = blockIdx.x;
  const int ht = bid & 31;
  const int b = (bid >> 5) & 3;
  const int br = bid >> 7;
  const unsigned short* inp = br ? in1 : in0;
  const unsigned short* wbr = wt + (size_t)br * NCHUNK * 9 * 8192;
  const float* scale = bnb + br * 256;
  const float* shiftp = scale + 128;
  unsigned short* outp = br ? out1 : out0;
  const int tid = threadIdx.x;
  const int lane = tid & 63, wv = tid >> 6;
  const int l31 = lane & 31, hi = lane >> 5;
  const int hi16 = hi * 16;
  const int wn = (wv >> 2) * 64;        // 0 or 64 (row group)
  const int cob = (wv & 3) * 32;        // co group
  const int rowb = wv >> 2;             // output row within block
  const int h0 = ht * 2;
  const int total = 9 * NCHUNK;
  const size_t wq = (size_t)((wv & 3) * 4) * 512 + lane * 8;

  f32x16 acc[2];
  acc[0] = (f32x16)0.f;
  acc[1] = (f32x16)0.f;
  u16x8 bv0[4], bv1[4];

  auto stageA = [&](int c) {  // 36 KB linear gload from pre-swizzled global
    const char* sr =
        (const char*)(inp + (((size_t)(b * NCHUNK + c) * 66 + h0) * 72) * 64);
    char* db = (char*)Awin;
#pragma unroll
    for (int i = 0; i < 4; ++i)
      gload16(sr + i * 8192 + tid * 16, db + i * 8192 + tid * 16);
    if (tid < 256) gload16(sr + 32768 + tid * 16, db + 32768 + tid * 16);
  };
  auto loadW = [&](u16x8 (&s)[4], int T) {
    const unsigned short* wtap = wbr + (size_t)T * 8192;
#pragma unroll
    for (int s4 = 0; s4 < 4; ++s4) s[s4] = ld8(wtap + (size_t)s4 * 512 + wq);
  };
  auto compute_tap = [&](int ty, int tx, u16x8 (&bvc)[4], int Tr, bool rld) {
    const char* ab = (const char*)Awin;
    const unsigned short* wr = wbr + (size_t)Tr * 8192;
    int abase[2], akey[2];
#pragma unroll
    for (int mf = 0; mf < 2; ++mf) {
      int col = mf * 32 + l31 + tx;
      abase[mf] = ((rowb + ty) * 72 + col) << 7;
      akey[mf] = ((col ^ (col >> 3)) & 7) << 4;
    }
#pragma unroll
    for (int s = 0; s < 4; ++s) {
      const int ko = s * 32 + hi16;
      u16x8 av0 = *(const u16x8*)(ab + abase[0] + (ko ^ akey[0]));
      u16x8 av1 = *(const u16x8*)(ab + abase[1] + (ko ^ akey[1]));
      u16x8 bb = bvc[s];
      acc[0] = mfma32(av0, bb, acc[0]);
      acc[1] = mfma32(av1, bb, acc[1]);
      if (rld) bvc[s] = ld8(wr + (size_t)s * 512 + wq);
    }
  };
  auto do_chunk = [&](int c, bool odd) {
#pragma unroll
    for (int t = 0; t < 9; ++t) {
      const int T = c * 9 + t;
      const bool rld = (T + 2 < total);
      if (((t & 1) != 0) == odd)  // T even -> set bv0
        compute_tap(t / 3, t - (t / 3) * 3, bv0, T + 2, rld);
      else
        compute_tap(t / 3, t - (t / 3) * 3, bv1, T + 2, rld);
    }
  };
  auto boundary = [&](int cn) {
    if (cn < NCHUNK) {
      asm volatile("s_waitcnt lgkmcnt(0)" ::: "memory");
      __builtin_amdgcn_s_barrier();
      stageA(cn);
      asm volatile("s_waitcnt vmcnt(0)" ::: "memory");
      __builtin_amdgcn_s_barrier();
    }
  };

  // prologue
  stageA(0);
  loadW(bv0, 0);
  loadW(bv1, 1);
  asm volatile("s_waitcnt vmcnt(0)" ::: "memory");
  __builtin_amdgcn_s_barrier();

#pragma unroll 1
  for (int c = 0; c < NCHUNK; c += 2) {
    do_chunk(c, false);
    boundary(c + 1);
    do_chunk(c + 1, true);
    boundary(c + 2);
  }

  // epilogue: BN + ReLU + flat NHWC store
  const int co = cob + l31;
  const float sc = scale[co], sh = shiftp[co];
#pragma unroll
  for (int mf = 0; mf < 2; ++mf)
#pragma unroll
    for (int r = 0; r < 16; ++r) {
      int n = wn + mf * 32 + (r & 3) + 8 * (r >> 2) + 4 * hi;
      float y = acc[mf][r] * sc + sh;
      y = y > 0.f ? y : 0.f;
      outp[((size_t)b * 4096 + (size_t)(h0 + (n >> 6)) * 64 + (n & 63)) * 128 + co] =
          f2bf(y);
    }
}

// ---------------- PAM Q/K/V 1x1 projections (MFMA) ----------------
__global__ __launch_bounds__(256) void k_qkv(
    const unsigned short* __restrict__ fp0, const unsigned short* __restrict__ qkw,
    const unsigned short* __restrict__ vww, const float* __restrict__ qb,
    const float* __restrict__ kb, const float* __restrict__ vb,
    unsigned short* __restrict__ Q, unsigned short* __restrict__ K,
    unsigned short* __restrict__ V2) {
  const int bid = blockIdx.x;
  const int nt = bid & 63, b = bid >> 6;
  const int lane = threadIdx.x & 63, wv = threadIdx.x >> 6;
  const int lg = lane >> 4, l15 = lane & 15;
  const int n = nt * 64 + wv * 16 + l15;
  const unsigned short* fbase = fp0 + ((size_t)b * 4096 + n) * 128 + lg * 8;
  f32x4 vacc[8];
#pragma unroll
  for (int mf = 0; mf < 8; ++mf) vacc[mf] = (f32x4){0.f, 0.f, 0.f, 0.f};
  f32x4 qacc = {0.f, 0.f, 0.f, 0.f}, kacc = {0.f, 0.f, 0.f, 0.f};
#pragma unroll
  for (int kc = 0; kc < 128; kc += 32) {
    u16x8 fb = ld8(fbase + kc);
    u16x8 qa = ld8(qkw + (size_t)l15 * 128 + lg * 8 + kc);
    u16x8 ka = ld8(qkw + 2048 + (size_t)l15 * 128 + lg * 8 + kc);
    qacc = mfma16(qa, fb, qacc);
    kacc = mfma16(ka, fb, kacc);
#pragma unroll
    for (int mf = 0; mf < 8; ++mf) {
      u16x8 va = ld8(vww + (size_t)(mf * 16 + l15) * 128 + lg * 8 + kc);
      vacc[mf] = mfma16(va, fb, vacc[mf]);
    }
  }
  const float LOG2E = 1.44269504088896f;
#pragma unroll
  for (int r = 0; r < 4; ++r) {
    int cq = lg * 4 + r;
    Q[(size_t)(b * 4096 + n) * 16 + cq] = f2bf((qacc[r] + qb[cq]) * LOG2E);
    K[(size_t)(b * 4096 + n) * 16 + cq] = f2bf(kacc[r] + kb[cq]);
  }
#pragma unroll
  for (int mf = 0; mf < 8; ++mf)
#pragma unroll
    for (int r = 0; r < 4; ++r) {
      int c = mf * 16 + lg * 4 + r;
      V2[((size_t)(b * 512 + (n >> 3)) * 128 + c) * 8 + (n & 7)] =
          f2bf(vacc[mf][r] + vb[c]);
    }
}

// ---------------- PAM attention: split-m, register-only body --------------
__global__ __launch_bounds__(512, 1) void k_pam(
    const unsigned short* __restrict__ Q, const unsigned short* __restrict__ K,
    const unsigned short* __restrict__ V2, const unsigned short* __restrict__ fp0,
    unsigned short* __restrict__ fp1, const float* __restrict__ pg) {
  __shared__ float obuf[2][3][16][64][4];  // 96 KB partial-O
  __shared__ float lred[8][64];            // denom partials
  const int bid = blockIdx.x;  // 4b * 64qt
  const int qt = bid & 63, b = bid >> 6;
  const int tid = threadIdx.x;
  const int lane = tid & 63, wv = tid >> 6;
  const int qsub = wv >> 2, mq = wv & 3;
  const int l31 = lane & 31, hi = lane >> 5;
  const int q0 = qt * 64 + qsub * 32;
  const unsigned short* Qp = Q + (size_t)b * 65536;
  const unsigned short* Kp = K + (size_t)b * 65536;
  const unsigned short* Vp = V2 + (size_t)b * 524288;
  const int hi8 = hi * 8;

  const u16x8 qB = ld8(Qp + (size_t)(q0 + l31) * 16 + hi8);

  f32x16 oacc[4];
#pragma unroll
  for (int ch = 0; ch < 4; ++ch) oacc[ch] = (f32x16)0.f;
  float dsum = 0.f;

  auto loadK = [&](int t) -> u16x8 {
    return ld8(Kp + (size_t)(t * 32 + l31) * 16 + hi8);
  };
  auto loadV = [&](int t, u16x8 (&vf)[8]) {
#pragma unroll
    for (int kc = 0; kc < 2; ++kc)
#pragma unroll
      for (int ch = 0; ch < 4; ++ch)
        vf[kc * 4 + ch] =
            ld8(Vp + (size_t)(t * 4 + kc * 2 + hi) * 1024 + (ch * 32 + l31) * 8);
  };
  auto body = [&](u16x8 kA, u16x8 (&vf)[8]) {
    f32x16 pacc = mfma32(kA, qB, (f32x16)0.f);
    float p[16];
#pragma unroll
    for (int r = 0; r < 16; ++r) p[r] = exp2f(pacc[r]);
    dsum += (((p[0] + p[1]) + (p[2] + p[3])) + ((p[4] + p[5]) + (p[6] + p[7]))) +
            (((p[8] + p[9]) + (p[10] + p[11])) + ((p[12] + p[13]) + (p[14] + p[15])));
    unsigned X[8], S[8];
#pragma unroll
    for (int j = 0; j < 8; ++j) X[j] = cvt_pk_bf16(p[2 * j], p[2 * j + 1]);
#pragma unroll
    for (int j = 0; j < 8; ++j) S[j] = __shfl_xor(X[j], 32, 64);
    const bool hc = hi != 0;
    u32x4v w0, w1;
    w0[0] = hc ? S[2] : X[0];
    w0[1] = hc ? S[3] : X[1];
    w0[2] = hc ? X[2] : S[0];
    w0[3] = hc ? X[3] : S[1];
    w1[0] = hc ? S[6] : X[4];
    w1[1] = hc ? S[7] : X[5];
    w1[2] = hc ? X[6] : S[4];
    w1[3] = hc ? X[7] : S[5];
    u16x8 f0 = __builtin_bit_cast(u16x8, w0);
    u16x8 f1 = __builtin_bit_cast(u16x8, w1);
#pragma unroll
    for (int ch = 0; ch < 4; ++ch) oacc[ch] = mfma32(f0, vf[ch], oacc[ch]);
#pragma unroll
    for (int ch = 0; ch < 4; ++ch) oacc[ch] = mfma32(f1, vf[4 + ch], oacc[ch]);
  };

  const int t0 = mq * 32;
  u16x8 kA0 = loadK(t0), kA1;
  u16x8 vf0[8], vf1[8];
  loadV(t0, vf0);
#pragma unroll 1
  for (int t = 0; t < 32; t += 2) {
    kA1 = loadK(t0 + t + 1);
    loadV(t0 + t + 1, vf1);
    body(kA0, vf0);
    if (t + 2 < 32) {
      kA0 = loadK(t0 + t + 2);
      loadV(t0 + t + 2, vf0);
    }
    body(kA1, vf1);
  }

  dsum += __shfl_xor(dsum, 32, 64);
  lred[wv][lane] = dsum;
  if (mq) {
#pragma unroll
    for (int ch = 0; ch < 4; ++ch)
#pragma unroll
      for (int j = 0; j < 4; ++j) {
        f32x4 v = {oacc[ch][4 * j + 0], oacc[ch][4 * j + 1], oacc[ch][4 * j + 2],
                   oacc[ch][4 * j + 3]};
        *reinterpret_cast<f32x4*>(&obuf[qsub][mq - 1][ch * 4 + j][lane][0]) = v;
      }
  }
  __syncthreads();
  if (mq == 0) {
    const float dtot = lred[qsub * 4 + 0][lane] + lred[qsub * 4 + 1][lane] +
                       lred[qsub * 4 + 2][lane] + lred[qsub * 4 + 3][lane];
#pragma unroll
    for (int ch = 0; ch < 4; ++ch)
#pragma unroll
      for (int j = 0; j < 4; ++j) {
        f32x4 s0 = *reinterpret_cast<const f32x4*>(&obuf[qsub][0][ch * 4 + j][lane][0]);
        f32x4 s1 = *reinterpret_cast<const f32x4*>(&obuf[qsub][1][ch * 4 + j][lane][0]);
        f32x4 s2 = *reinterpret_cast<const f32x4*>(&obuf[qsub][2][ch * 4 + j][lane][0]);
#pragma unroll
        for (int r = 0; r < 4; ++r)
          oacc[ch][4 * j + r] += (s0[r] + s1[r]) + s2[r];
      }
    const float rden = 1.f / dtot;
    const float gm = pg[0];
    float rdr[16];
#pragma unroll
    for (int r = 0; r < 16; ++r)
      rdr[r] = __shfl(rden, (r & 3) + 8 * (r >> 2) + 4 * hi, 64);
#pragma unroll
    for (int ch = 0; ch < 4; ++ch) {
      const int c = ch * 32 + l31;
#pragma unroll
      for (int r = 0; r < 16; ++r) {
        const int n = q0 + (r & 3) + 8 * (r >> 2) + 4 * hi;
        const int wp = (n & 63) + 1;
        float o = gm * oacc[ch][r] * rdr[r] +
                  bf2f(fp0[((size_t)b * 4096 + n) * 128 + c]);
        fp1[(((size_t)(b * 2 + (c >> 6)) * 66 + (n >> 6) + 1) * 72 + wp) * 64 +
            ((c & 63) ^ swzkey8(wp))] = f2bf(o);
      }
    }
  }
}

// ---------------- CAM Gram partials (fp32 VALU) ----------------
__global__ __launch_bounds__(256) void k_gram(const unsigned short* __restrict__ fc0,
                                              float* __restrict__ Gp) {
  __shared__ float fl[32][132];
  const int bid = blockIdx.x;
  const int nc = bid & 63, b = bid >> 6;
  const int t = threadIdx.x;
  const int i = t >> 1, jh = (t & 1) * 64;
  float acc[64];
#pragma unroll
  for (int j = 0; j < 64; ++j) acc[j] = 0.f;
  for (int c2 = 0; c2 < 2; ++c2) {
    const int n0 = nc * 64 + c2 * 32;
    {
      int nn = t >> 3, kh = t & 7;
      const unsigned short* src = fc0 + ((size_t)b * 4096 + n0 + nn) * 128 + kh * 16;
      u16x8 v0 = ld8(src), v1 = ld8(src + 8);
#pragma unroll
      for (int e = 0; e < 8; ++e) {
        fl[nn][kh * 16 + e] = bf2f(v0[e]);
        fl[nn][kh * 16 + 8 + e] = bf2f(v1[e]);
      }
    }
    __syncthreads();
    for (int nn = 0; nn < 32; ++nn) {
      float fi = fl[nn][i];
      const float4* row = reinterpret_cast<const float4*>(&fl[nn][jh]);
#pragma unroll
      for (int j4 = 0; j4 < 16; ++j4) {
        float4 fv = row[j4];
        acc[4 * j4 + 0] += fi * fv.x;
        acc[4 * j4 + 1] += fi * fv.y;
        acc[4 * j4 + 2] += fi * fv.z;
        acc[4 * j4 + 3] += fi * fv.w;
      }
    }
    __syncthreads();
  }
  float* dst = Gp + (((size_t)b * 64 + nc) * 128 + i) * 128 + jh;
  float4* dst4 = reinterpret_cast<float4*>(dst);
#pragma unroll
  for (int j4 = 0; j4 < 16; ++j4)
    dst4[j4] = make_float4(acc[4 * j4], acc[4 * j4 + 1], acc[4 * j4 + 2], acc[4 * j4 + 3]);
}

// ---------------- CAM reduce + softmax (fp32) ----------------
__global__ __launch_bounds__(128) void k_softm(const float* __restrict__ Gp,
                                               unsigned short* __restrict__ attn) {
  const int bid = blockIdx.x;
  const int i = bid & 127, b = bid >> 7;
  const int j = threadIdx.x;
  float g = 0.f;
  for (int nc = 0; nc < 64; ++nc) g += Gp[(((size_t)b * 64 + nc) * 128 + i) * 128 + j];
  __shared__ float red[2], red2[2];
  float m = g;
  m = fmaxf(m, __shfl_xor(m, 1, 64));
  m = fmaxf(m, __shfl_xor(m, 2, 64));
  m = fmaxf(m, __shfl_xor(m, 4, 64));
  m = fmaxf(m, __shfl_xor(m, 8, 64));
  m = fmaxf(m, __shfl_xor(m, 16, 64));
  m = fmaxf(m, __shfl_xor(m, 32, 64));
  const int wvi = j >> 6;
  if ((j & 63) == 0) red[wvi] = m;
  __syncthreads();
  m = fmaxf(red[0], red[1]);
  float e = __expf(g - m);
  float s = e;
  s += __shfl_xor(s, 1, 64);
  s += __shfl_xor(s, 2, 64);
  s += __shfl_xor(s, 4, 64);
  s += __shfl_xor(s, 8, 64);
  s += __shfl_xor(s, 16, 64);
  s += __shfl_xor(s, 32, 64);
  if ((j & 63) == 0) red2[wvi] = s;
  __syncthreads();
  s = red2[0] + red2[1];
  attn[((size_t)b * 128 + i) * 128 + j] = f2bf(e / s);
}

// ---------------- CAM out: attn @ f, residual (MFMA) ----------------
__global__ __launch_bounds__(256) void k_camout(
    const unsigned short* __restrict__ fc0, const unsigned short* __restrict__ attn,
    const float* __restrict__ cg, unsigned short* __restrict__ fc1) {
  const int bid = blockIdx.x;
  const int nt = bid & 63, b = bid >> 6;
  const int lane = threadIdx.x & 63, wv = threadIdx.x >> 6;
  const int lg = lane >> 4, l15 = lane & 15;
  const int n = nt * 64 + wv * 16 + l15;
  const unsigned short* fbase = fc0 + ((size_t)b * 4096 + n) * 128 + lg * 8;
  const unsigned short* abase = attn + (size_t)b * 16384 + lg * 8;
  f32x4 acc[8];
#pragma unroll
  for (int mf = 0; mf < 8; ++mf) acc[mf] = (f32x4){0.f, 0.f, 0.f, 0.f};
#pragma unroll
  for (int kc = 0; kc < 128; kc += 32) {
    u16x8 fb = ld8(fbase + kc);
#pragma unroll
    for (int mf = 0; mf < 8; ++mf) {
      u16x8 aa = ld8(abase + (size_t)(mf * 16 + l15) * 128 + kc);
      acc[mf] = mfma16(aa, fb, acc[mf]);
    }
  }
  const float gm = cg[0];
  const int nn = nt * 64 + wv * 16 + l15;
  const int wp = (nn & 63) + 1;
  const int key8 = swzkey8(wp);
#pragma unroll
  for (int mf = 0; mf < 8; ++mf)
#pragma unroll
    for (int r = 0; r < 4; ++r) {
      int c = mf * 16 + lg * 4 + r;
      float o = gm * acc[mf][r] + bf2f(fc0[((size_t)b * 4096 + nn) * 128 + c]);
      fc1[(((size_t)(b * 2 + (c >> 6)) * 66 + (nn >> 6) + 1) * 72 + wp) * 64 +
          ((c & 63) ^ key8)] = f2bf(o);
    }
}

// ---------------- classifier heads (MFMA, fp32 out) ----------------
__global__ __launch_bounds__(256) void k_heads(
    const unsigned short* __restrict__ fp2, const unsigned short* __restrict__ fc2,
    const unsigned short* __restrict__ hw, const float* __restrict__ clsb,
    const float* __restrict__ apb, const float* __restrict__ acb,
    float* __restrict__ out) {
  const int bid = blockIdx.x;
  const int nt = bid & 63, b = bid >> 6;
  const int lane = threadIdx.x & 63, wv = threadIdx.x >> 6;
  const int lg = lane >> 4, l15 = lane & 15;
  const int n = nt * 64 + wv * 16 + l15;
  const unsigned short* pb = fp2 + (size_t)(b * 4096 + n) * 128 + lg * 8;
  const unsigned short* cb = fc2 + (size_t)(b * 4096 + n) * 128 + lg * 8;
  f32x4 acc[3][2];
#pragma unroll
  for (int hd = 0; hd < 3; ++hd)
#pragma unroll
    for (int mf = 0; mf < 2; ++mf) acc[hd][mf] = (f32x4){0.f, 0.f, 0.f, 0.f};
#pragma unroll
  for (int kc = 0; kc < 128; kc += 32) {
    u16x8 vp = ld8(pb + kc);
    u16x8 vc = ld8(cb + kc);
    u16x8 vs;
#pragma unroll
    for (int e = 0; e < 8; ++e) vs[e] = f2bf(bf2f(vp[e]) + bf2f(vc[e]));
#pragma unroll
    for (int mf = 0; mf < 2; ++mf) {
      u16x8 a0 = ld8(hw + (size_t)(0 * 32 + mf * 16 + l15) * 128 + lg * 8 + kc);
      u16x8 a1 = ld8(hw + (size_t)(1 * 32 + mf * 16 + l15) * 128 + lg * 8 + kc);
      u16x8 a2 = ld8(hw + (size_t)(2 * 32 + mf * 16 + l15) * 128 + lg * 8 + kc);
      acc[0][mf] = mfma16(a0, vs, acc[0][mf]);
      acc[1][mf] = mfma16(a1, vp, acc[1][mf]);
      acc[2][mf] = mfma16(a2, vc, acc[2][mf]);
    }
  }
  const float* bias[3] = {clsb, apb, acb};
  const size_t hoff[3] = {0, 311296, 622592};
#pragma unroll
  for (int hd = 0; hd < 3; ++hd)
#pragma unroll
    for (int mf = 0; mf < 2; ++mf)
#pragma unroll
      for (int r = 0; r < 4; ++r) {
        int co = mf * 16 + lg * 4 + r;
        if (co < 19)
          out[hoff[hd] + ((size_t)b * 19 + co) * 4096 + n] = acc[hd][mf][r] + bias[hd][co];
      }
}

// ---------------------------------------------------------------------------
extern "C" void kernel_launch(void* const* d_in, const int* in_sizes, int n_in,
                              void* d_out, int out_size, void* d_ws, size_t ws_size,
                              hipStream_t stream) {
  (void)in_sizes; (void)n_in; (void)out_size; (void)ws_size;
  const float* x = (const float*)d_in[0];
  const float* wp1 = (const float*)d_in[1];
  const float* g1p = (const float*)d_in[2];
  const float* b1p = (const float*)d_in[3];
  const float* m1p = (const float*)d_in[4];
  const float* v1p = (const float*)d_in[5];
  const float* qw = (const float*)d_in[6];
  const float* qb = (const float*)d_in[7];
  const float* kw = (const float*)d_in[8];
  const float* kb = (const float*)d_in[9];
  const float* vw = (const float*)d_in[10];
  const float* vb = (const float*)d_in[11];
  const float* pamg = (const float*)d_in[12];
  const float* wp2 = (const float*)d_in[13];
  const float* g2p = (const float*)d_in[14];
  const float* b2p = (const float*)d_in[15];
  const float* m2p = (const float*)d_in[16];
  const float* v2p = (const float*)d_in[17];
  const float* wc1 = (const float*)d_in[18];
  const float* g1c = (const float*)d_in[19];
  const float* b1c = (const float*)d_in[20];
  const float* m1c = (const float*)d_in[21];
  const float* v1c = (const float*)d_in[22];
  const float* camg = (const float*)d_in[23];
  const float* wc2 = (const float*)d_in[24];
  const float* g2c = (const float*)d_in[25];
  const float* b2c = (const float*)d_in[26];
  const float* m2c = (const float*)d_in[27];
  const float* v2c = (const float*)d_in[28];
  const float* clsw = (const float*)d_in[29];
  const float* clsb = (const float*)d_in[30];
  const float* apw = (const float*)d_in[31];
  const float* apb = (const float*)d_in[32];
  const float* acw = (const float*)d_in[33];
  const float* acb = (const float*)d_in[34];

  char* ws = (char*)d_ws;
  unsigned short* xt = (unsigned short*)(ws + OFF_XT);
  unsigned short* fp1 = (unsigned short*)(ws + OFF_FP1);
  unsigned short* fc1 = (unsigned short*)(ws + OFF_FC1);
  unsigned short* fp0 = (unsigned short*)(ws + OFF_FP0);
  unsigned short* fc0 = (unsigned short*)(ws + OFF_FC0);
  unsigned short* fp2 = (unsigned short*)(ws + OFF_FP2);
  unsigned short* fc2 = (unsigned short*)(ws + OFF_FC2);
  unsigned short* wt1 = (unsigned short*)(ws + OFF_WT1);
  unsigned short* wt2 = (unsigned short*)(ws + OFF_WT2);
  unsigned short* qkw = (unsigned short*)(ws + OFF_QKW);
  unsigned short* vww = (unsigned short*)(ws + OFF_VWW);
  unsigned short* hww = (unsigned short*)(ws + OFF_HWW);
  float* bnss = (float*)(ws + OFF_BNSS);
  unsigned short* Qb = (unsigned short*)(ws + OFF_Q);
  unsigned short* Kb = (unsigned short*)(ws + OFF_K);
  unsigned short* Vb = (unsigned short*)(ws + OFF_V);
  unsigned short* attnb = (unsigned short*)(ws + OFF_ATTN);
  float* Gp = (float*)(ws + OFF_XT);  // alias: xt dead after conv1

  // zero chunked (padded) buffers: xt + fp1 + fc1
  hipMemsetAsync(ws, 0, ZERO_BYTES, stream);

  PackArgs pa;
  pa.wp1 = wp1; pa.wc1 = wc1; pa.wp2 = wp2; pa.wc2 = wc2;
  pa.qw = qw; pa.kw = kw; pa.vw = vw; pa.clsw = clsw; pa.apw = apw; pa.acw = acw;
  pa.g1p = g1p; pa.b1p = b1p; pa.m1p = m1p; pa.v1p = v1p;
  pa.g1c = g1c; pa.b1c = b1c; pa.m1c = m1c; pa.v1c = v1c;
  pa.g2p = g2p; pa.b2p = b2p; pa.m2p = m2p; pa.v2p = v2p;
  pa.g2c = g2c; pa.b2c = b2c; pa.m2c = m2c; pa.v2c = v2c;
  pa.wt1 = wt1; pa.wt2 = wt2; pa.qkw = qkw; pa.vww = vww; pa.hww = hww; pa.bnss = bnss;
  k_pack<<<5892, 256, 0, stream>>>(pa);

  k_xpose<<<1024, 256, 0, stream>>>(x, xt);

  k_conv3x3<8><<<256, 512, 0, stream>>>(xt, xt, wt1, bnss, fp0, fc0);

  k_qkv<<<256, 256, 0, stream>>>(fp0, qkw, vww, qb, kb, vb, Qb, Kb, Vb);
  k_gram<<<256, 256, 0, stream>>>(fc0, Gp);
  k_pam<<<256, 512, 0, stream>>>(Qb, Kb, Vb, fp0, fp1, pamg);
  k_softm<<<512, 128, 0, stream>>>(Gp, attnb);
  k_camout<<<256, 256, 0, stream>>>(fc0, attnb, camg, fc1);

  k_conv3x3<2><<<256, 512, 0, stream>>>(fp1, fc1, wt2, bnss + 512, fp2, fc2);

  k_heads<<<256, 256, 0, stream>>>(fp2, fc2, hww, clsb, apb, acb, (float*)d_out);
}